// Round 8
// baseline (358.459 us; speedup 1.0000x reference)
//
#include <hip/hip_runtime.h>
#include <hip/hip_bf16.h>
#include <math.h>

#define NB 8
#define NT 1024
#define ND 768
#define NH 12
#define HD 64
#define WINDOW 768
#define LN_EPS 1e-5f
#define NEGF -3.4028234663852886e38f
#define SCL2 0.18033688011112042f   // 0.125 * log2(e)

static const int BT = NB * NT;  // 8192 rows

typedef __bf16 bf16x8 __attribute__((ext_vector_type(8)));
typedef float  f32x4  __attribute__((ext_vector_type(4)));
typedef unsigned short ushort_t;

__device__ __forceinline__ unsigned short f2bf(float f) {
    __hip_bfloat16 h = __float2bfloat16(f);
    return __builtin_bit_cast(unsigned short, h);
}

// async global->LDS, 16B per lane. LDS dest = wave-uniform base + lane*16.
__device__ __forceinline__ void load_lds16(const void* g, void* l) {
    __builtin_amdgcn_global_load_lds((const __attribute__((address_space(1))) unsigned int*)g,
                                     (__attribute__((address_space(3))) unsigned int*)l,
                                     16, 0, 0);
}

// inline-asm ds_read_b128 with compile-time offset immediate: ONE base VGPR serves
// all fragment reads of a class (slot + subtile folded into offset:IMM).
template <int IMM>
__device__ __forceinline__ bf16x8 ds_read16o(unsigned base) {
    bf16x8 r;
    asm volatile("ds_read_b128 %0, %1 offset:%2" : "=v"(r) : "v"(base), "n"(IMM));
    return r;
}

// ---------------- all weight transposes fused: wT[n][k] = bf16(w[k][n]) --------
__global__ __launch_bounds__(256) void transpose_all(const float* __restrict__ w0, ushort_t* __restrict__ t0v,
                                                     const float* __restrict__ w1, ushort_t* __restrict__ t1v,
                                                     const float* __restrict__ w2, ushort_t* __restrict__ t2v,
                                                     const float* __restrict__ w3, ushort_t* __restrict__ t3v) {
    int bid = blockIdx.x;
    const float* w; ushort_t* wt; int K, N;
    if (bid < 1728)                    { w = w0; wt = t0v; K = 768;  N = 2304; }
    else if ((bid -= 1728) < 576)      { w = w1; wt = t1v; K = 768;  N = 768;  }
    else if ((bid -= 576) < 2304)      { w = w2; wt = t2v; K = 768;  N = 3072; }
    else       { bid -= 2304;            w = w3; wt = t3v; K = 3072; N = 768;  }
    const int nxt = N / 32;
    const int n0 = (bid % nxt) * 32, k0 = (bid / nxt) * 32;
    __shared__ float t[32][33];
    const int tx = threadIdx.x & 31, ty = threadIdx.x >> 5;  // 32 x 8
    for (int r = ty; r < 32; r += 8)
        t[r][tx] = w[(size_t)(k0 + r) * N + n0 + tx];
    __syncthreads();
    for (int r = ty; r < 32; r += 8)
        wt[(size_t)(n0 + r) * K + k0 + tx] = f2bf(t[tx][r]);
}

// ---------------- V transpose (pi-permuted keys): vT[b][h][d][t'] --------------
__global__ __launch_bounds__(256) void transpose_v(const ushort_t* __restrict__ qkvb,
                                                   ushort_t* __restrict__ vT) {
    const int t0 = blockIdx.x * 64;
    const int h = blockIdx.y, b = blockIdx.z;
    __shared__ ushort_t sm[64 * 72];
    const int tid = threadIdx.x;
    #pragma unroll
    for (int p = 0; p < 2; p++) {
        int idx = p * 256 + tid;
        int r = idx >> 3, c = idx & 7;
        *(bf16x8*)&sm[r * 72 + c * 8] =
            *(const bf16x8*)(qkvb + (size_t)(b * NT + t0 + r) * (3 * ND) + 2 * ND + h * HD + c * 8);
    }
    __syncthreads();
    #pragma unroll
    for (int p = 0; p < 2; p++) {
        int idx = p * 256 + tid;
        int d = idx >> 3, c2 = idx & 7;
        ushort_t tmp[8];
        #pragma unroll
        for (int j = 0; j < 8; j++) {
            int kp = c2 * 8 + j;
            int key = ((kp & 1) << 4) | ((kp >> 1) & 15) | (kp & 32);
            tmp[j] = sm[key * 72 + d];
        }
        *(bf16x8*)(vT + ((size_t)((b * NH + h) * HD + d)) * NT + t0 + c2 * 8) = *(bf16x8*)tmp;
    }
}

// ---------------- LayerNorm -> bf16: wave-per-row, shuffle reduce --------------
__global__ __launch_bounds__(256) void ln_kernel(const float* __restrict__ x,
                                                 const float* __restrict__ w,
                                                 const float* __restrict__ b,
                                                 ushort_t* __restrict__ out) {
    const int row  = blockIdx.x * 4 + (threadIdx.x >> 6);
    const int lane = threadIdx.x & 63;
    const float* xr = x + (size_t)row * ND;

    float4 v[3];
    #pragma unroll
    for (int s = 0; s < 3; s++) v[s] = *(const float4*)(xr + s * 256 + lane * 4);

    float sum = 0.f;
    #pragma unroll
    for (int s = 0; s < 3; s++) sum += v[s].x + v[s].y + v[s].z + v[s].w;
    #pragma unroll
    for (int off = 1; off < 64; off <<= 1) sum += __shfl_xor(sum, off, 64);
    const float mu = sum * (1.0f / ND);

    float var = 0.f;
    #pragma unroll
    for (int s = 0; s < 3; s++) {
        float a0 = v[s].x - mu, a1 = v[s].y - mu, a2 = v[s].z - mu, a3 = v[s].w - mu;
        var += a0 * a0 + a1 * a1 + a2 * a2 + a3 * a3;
    }
    #pragma unroll
    for (int off = 1; off < 64; off <<= 1) var += __shfl_xor(var, off, 64);
    const float rstd = rsqrtf(var * (1.0f / ND) + LN_EPS);

    #pragma unroll
    for (int s = 0; s < 3; s++) {
        const int col = s * 256 + lane * 4;
        float4 w4 = *(const float4*)(w + col);
        float4 b4 = *(const float4*)(b + col);
        ushort4 r;
        r.x = f2bf((v[s].x - mu) * rstd * w4.x + b4.x);
        r.y = f2bf((v[s].y - mu) * rstd * w4.y + b4.y);
        r.z = f2bf((v[s].z - mu) * rstd * w4.z + b4.z);
        r.w = f2bf((v[s].w - mu) * rstd * w4.w + b4.w);
        *(ushort4*)(out + (size_t)row * ND + col) = r;
    }
}

// ---------------- bf16 MFMA GEMM, double-buffered pipeline (128x128) -----------
// Kept for the two N=768 GEMMs, with bijective XCD-chunk swizzle (grids %8==0).
// EPI: 1 = +bias+resid -> fp32
template <int EPI>
__global__ __launch_bounds__(256) void gemm_bt(const ushort_t* __restrict__ A,
                                               const ushort_t* __restrict__ Bt,
                                               const float* __restrict__ bias,
                                               const float* __restrict__ resid,
                                               void* __restrict__ Cout,
                                               int M, int N, int K) {
    __shared__ __align__(16) ushort_t smem[2][2][128 * 32];  // [buf][A/B][...]

    const int tid  = threadIdx.x;
    const int nwg   = gridDim.x * gridDim.y;
    const int flatb = blockIdx.y * gridDim.x + blockIdx.x;
    const int q8    = nwg >> 3;
    const int swz   = (flatb & 7) * q8 + (flatb >> 3);
    const int bm   = (swz / gridDim.x) * 128;
    const int bn   = (swz % gridDim.x) * 128;
    const int lane = tid & 63;
    const int wave = tid >> 6;
    const int wm   = (wave & 1) * 64;
    const int wn   = (wave >> 1) * 64;
    const int fcol = lane & 15;
    const int quad = lane >> 4;

    f32x4 acc[4][4] = {};

    const int srow = tid >> 2, scg = (tid & 3) * 8;

    auto issue = [&](int k0, int buf) {
        #pragma unroll
        for (int p = 0; p < 2; p++) {
            const int row = srow + p * 64;
            const int flat = (p * 256 + tid) * 8;
            load_lds16(A  + (size_t)(bm + row) * K + k0 + scg, &smem[buf][0][flat]);
            load_lds16(Bt + (size_t)(bn + row) * K + k0 + scg, &smem[buf][1][flat]);
        }
    };

    issue(0, 0);
    const int KT = K >> 5;
    for (int kt = 0; kt < KT; kt++) {
        const int cur = kt & 1;
        __syncthreads();
        if (kt + 1 < KT) issue((kt + 1) << 5, cur ^ 1);

        bf16x8 a[4], b[4];
        #pragma unroll
        for (int i = 0; i < 4; i++)
            a[i] = *(const bf16x8*)&smem[cur][0][(wm + i * 16 + fcol) * 32 + quad * 8];
        #pragma unroll
        for (int j = 0; j < 4; j++)
            b[j] = *(const bf16x8*)&smem[cur][1][(wn + j * 16 + fcol) * 32 + quad * 8];
        #pragma unroll
        for (int i = 0; i < 4; i++)
            #pragma unroll
            for (int j = 0; j < 4; j++)
                acc[i][j] = __builtin_amdgcn_mfma_f32_16x16x32_bf16(a[i], b[j], acc[i][j], 0, 0, 0);
    }

    if (EPI == 1) {
        #pragma unroll
        for (int j = 0; j < 4; j++) {
            const int gcol = bn + wn + j * 16 + fcol;
            const float bs = bias[gcol];
            #pragma unroll
            for (int i = 0; i < 4; i++) {
                #pragma unroll
                for (int r = 0; r < 4; r++) {
                    const int grow = bm + wm + i * 16 + quad * 4 + r;
                    float val = acc[i][j][r] + bs + resid[(size_t)grow * N + gcol];
                    ((float*)Cout)[(size_t)grow * N + gcol] = val;
                }
            }
        }
    } else {
        __syncthreads();
        ushort_t* Cs = &smem[0][0][0] + wave * (64 * 40);
        #pragma unroll
        for (int hh = 0; hh < 2; hh++) {
            #pragma unroll
            for (int jj = 0; jj < 2; jj++) {
                const int j = hh * 2 + jj;
                const float bs = bias[bn + wn + j * 16 + fcol];
                #pragma unroll
                for (int i = 0; i < 4; i++) {
                    #pragma unroll
                    for (int r = 0; r < 4; r++) {
                        float val = acc[i][j][r] + bs;
                        if (EPI == 2) {
                            float y = 0.7978845608028654f * (val + 0.044715f * val * val * val);
                            float t = 1.0f - 2.0f / (1.0f + __expf(2.0f * y));
                            val = 0.5f * val * (1.0f + t);
                        }
                        const int lr = i * 16 + quad * 4 + r;
                        Cs[lr * 40 + jj * 16 + fcol] = f2bf(val);
                    }
                }
            }
            #pragma unroll
            for (int p = 0; p < 4; p++) {
                const int cid = p * 64 + lane;
                const int lr = cid >> 2, ck = cid & 3;
                bf16x8 vv = *(const bf16x8*)&Cs[lr * 40 + ck * 8];
                *(bf16x8*)((ushort_t*)Cout + (size_t)(bm + wm + lr) * N + bn + wn + hh * 32 + ck * 8) = vv;
            }
        }
    }
}

// ---------------- 128x256 BK=32 GEMM: counted-vmcnt + 2 blocks/CU --------------
// Round-7 kernel (harness-verified) with ONE change: the 4-slot in-row XOR
// swizzle (c^(r&3); 64B rows -> only 4 bank positions -> 4-way conflict, 4.92M
// SQ_LDS_BANK_CONFLICT) is replaced by an 8-slot ROW-PAIR swizzle:
//   phys(r,c) = (r>>1)*128 + ((((r&1)<<2)|c) ^ ((r>>1)&7)) * 16
// Each 128B row-pair cycles all 8 16B slots -> 2 lanes/slot per quarter-wave
// (2-way aliasing = free, m136), same property as the verified gemm256 layout.
// Write side inverts it on the GLOBAL source (rule #21: linear LDS dest);
// read-side: frag rows are base+fcol with base%16==0 so pair&7 == fcol>>1 and
// the subtile offset immediates (i*1024) are unchanged.
// Ledger (unchanged): stage = exactly 3 global_load_lds; VMW(3) counted waits.
// EPI: 0 = +bias -> bf16;  2 = +bias,gelu(tanh) -> bf16
template <int EPI, int NN, int KK>
__global__ __launch_bounds__(512, 4) void gemm128n(const ushort_t* __restrict__ A,
                                                   const ushort_t* __restrict__ Bt,
                                                   const float* __restrict__ bias,
                                                   ushort_t* __restrict__ Cout) {
    __shared__ __align__(16) ushort_t lds[24576];   // 48 KB: A 2x4096, B 2x8192 ushorts

    const int tid  = threadIdx.x;
    const int lane = tid & 63;
    const int wave = tid >> 6;     // 0..7
    const int wr   = wave >> 2;    // 0..1  (64-row half)
    const int wn   = wave & 3;     // 0..3  (64-col quarter)
    const int fcol = lane & 15;
    const int quad = lane >> 4;

    // bijective XCD-chunk swizzle (nwg = 576 / 768, both % 8 == 0)
    const int nwg   = gridDim.x * gridDim.y;
    const int flatb = blockIdx.y * gridDim.x + blockIdx.x;
    const int q8    = nwg >> 3;
    const int swz   = (flatb & 7) * q8 + (flatb >> 3);
    const int bm    = (swz / gridDim.x) * 128;
    const int bn    = (swz % gridDim.x) * 256;

    constexpr int KTILES = KK >> 5;   // 32-wide K tiles (24 for K=768)

    f32x4 acc[4][4] = {};             // 64 regs: wave's 64x64 output
    bf16x8 ra[4], rbv[4];

    // fragment-read bases (row-pair swizzle): pair = row>>1, pair&7 == fcol>>1
    // for all fragment rows (row = 16-multiple + fcol), so the XOR is lane-const.
    const unsigned ldsb = (unsigned)(size_t)(const __attribute__((address_space(3))) ushort_t*)lds;
    const unsigned slotr = (unsigned)(((((fcol & 1) << 2) | quad) ^ (fcol >> 1)) * 16);
    const unsigned baseA = ldsb + (unsigned)((wr * 32 + (fcol >> 1)) * 128) + slotr;
    const unsigned baseB = ldsb + 16384u + (unsigned)((wn * 32 + (fcol >> 1)) * 128) + slotr;

    auto stage = [&](int kt) {   // exactly 3 global_load_lds per thread
        const int kk = (kt < KTILES ? kt : 0) << 5;   // clamp keeps vmcnt ledger
        ushort_t* dstA = lds + (kt & 1) * 4096;
        {
            const int f = tid;                         // 512 loads cover 128x32
            const int pr = f >> 3, s2 = (f & 7) ^ (pr & 7);
            const int r = pr * 2 + (s2 >> 2), c = s2 & 3;
            load_lds16(A + (size_t)(bm + r) * KK + kk + c * 8, dstA + f * 8);
        }
        ushort_t* dstB = lds + 8192 + (kt & 1) * 8192;
        #pragma unroll
        for (int p = 0; p < 2; p++) {                  // 1024 loads cover 256x32
            const int f = (p << 9) + tid;
            const int pr = f >> 3, s2 = (f & 7) ^ (pr & 7);
            const int r = pr * 2 + (s2 >> 2), c = s2 & 3;
            load_lds16(Bt + (size_t)(bn + r) * KK + kk + c * 8, dstB + f * 8);
        }
    };

#define RD_T(CUR) {                                                        \
    ra[0]  = ds_read16o<(CUR) * 8192 + 0   >(baseA);                       \
    ra[1]  = ds_read16o<(CUR) * 8192 + 1024>(baseA);                       \
    ra[2]  = ds_read16o<(CUR) * 8192 + 2048>(baseA);                       \
    ra[3]  = ds_read16o<(CUR) * 8192 + 3072>(baseA);                       \
    rbv[0] = ds_read16o<(CUR) * 16384 + 0   >(baseB);                      \
    rbv[1] = ds_read16o<(CUR) * 16384 + 1024>(baseB);                      \
    rbv[2] = ds_read16o<(CUR) * 16384 + 2048>(baseB);                      \
    rbv[3] = ds_read16o<(CUR) * 16384 + 3072>(baseB); }
#define LGKM0() { asm volatile("s_waitcnt lgkmcnt(0)" ::: "memory");       \
    __builtin_amdgcn_sched_barrier(0); }
#define MMA16() {                                                          \
    __builtin_amdgcn_s_setprio(1);                                         \
    _Pragma("unroll") for (int i = 0; i < 4; i++)                          \
    _Pragma("unroll") for (int j = 0; j < 4; j++)                          \
        acc[i][j] = __builtin_amdgcn_mfma_f32_16x16x32_bf16(               \
            ra[i], rbv[j], acc[i][j], 0, 0, 0);                            \
    __builtin_amdgcn_s_setprio(0);                                         \
    __builtin_amdgcn_sched_barrier(0); }
#define VMW3() asm volatile("s_waitcnt vmcnt(3)" ::: "memory")
#define BARR() asm volatile("s_barrier" ::: "memory")

    stage(0); stage(1);
    VMW3();                       // tile0's 3 oldest loads landed
    BARR();

    #pragma unroll 1
    for (int it = 0; it < KTILES / 2; ++it) {
        const int t = it << 1;
        // even tile -> slot 0
        RD_T(0);
        LGKM0();
        MMA16();
        BARR();                   // all waves done reading slot 0
        stage(t + 2);             // overwrite slot 0 (WAR-safe)
        VMW3();                   // tile t+1 landed (own-wave)
        BARR();                   // publish block-wide
        // odd tile -> slot 1
        RD_T(1);
        LGKM0();
        MMA16();
        BARR();
        stage(t + 3);
        VMW3();
        BARR();
    }

    // full drain before LDS reuse
    asm volatile("s_waitcnt vmcnt(0) lgkmcnt(0)" ::: "memory");
    BARR();

    // epilogue: per-wave 32-row LDS staging (32x72 per wave = 36 KB total)
    ushort_t* Cs = lds + wave * (32 * 72);
    #pragma unroll
    for (int h = 0; h < 2; h++) {
        #pragma unroll
        for (int j = 0; j < 4; j++) {
            const float bs = bias[bn + wn * 64 + j * 16 + fcol];
            #pragma unroll
            for (int i2 = 0; i2 < 2; i2++) {
                #pragma unroll
                for (int r = 0; r < 4; r++) {
                    float val = acc[h * 2 + i2][j][r] + bs;
                    if (EPI == 2) {
                        float y = 0.7978845608028654f * (val + 0.044715f * val * val * val);
                        float t = 1.0f - 2.0f / (1.0f + __expf(2.0f * y));
                        val = 0.5f * val * (1.0f + t);
                    }
                    Cs[(i2 * 16 + quad * 4 + r) * 72 + j * 16 + fcol] = f2bf(val);
                }
            }
        }
        __builtin_amdgcn_sched_barrier(0);   // order within-wave store->load
        #pragma unroll
        for (int p = 0; p < 4; p++) {
            const int cid = (p << 6) + lane;
            const int lr = cid >> 3, ck = cid & 7;
            bf16x8 vv = *(const bf16x8*)&Cs[lr * 72 + ck * 8];
            *(bf16x8*)(Cout + (size_t)(bm + wr * 64 + h * 32 + lr) * NN + bn + wn * 64 + ck * 8) = vv;
        }
        __builtin_amdgcn_sched_barrier(0);
    }
#undef RD_T
#undef LGKM0
#undef MMA16
#undef VMW3
#undef BARR
}

// ---------------- MFMA flash attention: no-max softmax, l via ones-MFMA --------
__global__ __launch_bounds__(256) void flash_attn_mfma(const ushort_t* __restrict__ qkvb,
                                                       const ushort_t* __restrict__ vT,
                                                       const int* __restrict__ amask,
                                                       ushort_t* __restrict__ out) {
    const int qt = 15 - blockIdx.x;   // heavy tiles first
    const int h  = blockIdx.y;
    const int b  = blockIdx.z;
    const int q0 = qt * 64;

    __shared__ __align__(16) ushort_t QPs[64 * 64];      // Q, then reused for P
    __shared__ __align__(16) ushort_t Ks[2][64 * 64];
    __shared__ __align__(16) ushort_t Vts[2][64 * 64];

    const int tid  = threadIdx.x;
    const int lane = tid & 63;
    const int wave = tid >> 6;
    const int fcol = lane & 15;
    const int quad = lane >> 4;
    const int wq0  = wave * 16;

    #pragma unroll
    for (int p = 0; p < 2; p++) {
        int flat = p * 256 + tid;
        int r = flat >> 3, c = (flat & 7) ^ (r & 7);
        load_lds16(qkvb + (size_t)(b * NT + q0 + r) * (3 * ND) + h * HD + c * 8, &QPs[flat * 8]);
    }
    __syncthreads();

    bf16x8 aQ[2];
    {
        const int qr = wq0 + fcol;
        #pragma unroll
        for (int ks = 0; ks < 2; ks++) {
            int c = ks * 4 + quad;
            aQ[ks] = *(const bf16x8*)&QPs[qr * 64 + ((c ^ (qr & 7)) * 8)];
        }
    }

    bf16x8 bones;
    #pragma unroll
    for (int i = 0; i < 8; i++) bones[i] = (__bf16)1.0f;

    auto issueKV = [&](int cch, int buf) {
        const int kbase = cch * 64;
        #pragma unroll
        for (int p = 0; p < 2; p++) {
            int flat = p * 256 + tid;
            int r = flat >> 3, c = (flat & 7) ^ (r & 7);
            load_lds16(qkvb + (size_t)(b * NT + kbase + r) * (3 * ND) + ND + h * HD + c * 8,
                       &Ks[buf][flat * 8]);
            load_lds16(vT + ((size_t)((b * NH + h) * HD + r)) * NT + kbase + c * 8,
                       &Vts[buf][flat * 8]);
        }
    };

    f32x4 oacc[4] = {};
    f32x4 lacc = {};

    const int c_lo = (qt > 12) ? (qt - 12) : 0;
    issueKV(c_lo, 0);
    for (int cch = c_lo; cch <= qt; cch++) {
        const int cur = (cch - c_lo) & 1;
        const int kbase = cch * 64;
        __syncthreads();
        if (cch + 1 <= qt) issueKV(cch + 1, cur ^ 1);

        int am[4];
        #pragma unroll
        for (int jn = 0; jn < 4; jn++) am[jn] = amask[b * NT + kbase + jn * 16 + fcol];
        const int amok_lane = (am[0] != 0) & (am[1] != 0) & (am[2] != 0) & (am[3] != 0);
        const bool fast = (cch < qt) && (cch >= qt - 11) && __all(amok_lane);

        f32x4 sc[4] = {};
        #pragma unroll
        for (int ks = 0; ks < 2; ks++) {
            #pragma unroll
            for (int jn = 0; jn < 4; jn++) {
                const int kr = jn * 16 + fcol;
                bf16x8 bk = *(const bf16x8*)&Ks[cur][kr * 64 + (((ks * 4 + quad) ^ (kr & 7)) * 8)];
                sc[jn] = __builtin_amdgcn_mfma_f32_16x16x32_bf16(aQ[ks], bk, sc[jn], 0, 0, 0);
            }
        }

        float pvv[4][4];
        if (fast) {
            #pragma unroll
            for (int jn = 0; jn < 4; jn++)
                #pragma unroll
                for (int r = 0; r < 4; r++)
                    pvv[jn][r] = __builtin_amdgcn_exp2f(sc[jn][r] * SCL2);
        } else {
            #pragma unroll
            for (int jn = 0; jn < 4; jn++) {
                const int jg = kbase + jn * 16 + fcol;
                const bool amok = (am[jn] != 0);
                #pragma unroll
                for (int r = 0; r < 4; r++) {
                    const int ig = q0 + wq0 + quad * 4 + r;
                    bool keep = (jg <= ig) && (jg >= ig - (WINDOW - 1)) && amok;
                    float s = keep ? sc[jn][r] * SCL2 : -1e38f;
                    pvv[jn][r] = __builtin_amdgcn_exp2f(s);
                }
            }
        }

        #pragma unroll
        for (int half = 0; half < 2; half++) {
            const int cbase = half * 4 + (fcol >> 2);
            const int off = (fcol & 3) * 2;
            #pragma unroll
            for (int r = 0; r < 4; r++) {
                const int row = wq0 + quad * 4 + r;
                unsigned int pk = (unsigned int)f2bf(pvv[half * 2][r]) |
                                  ((unsigned int)f2bf(pvv[half * 2 + 1][r]) << 16);
                *(unsigned int*)&QPs[row * 64 + ((cbase ^ (row & 7)) * 8) + off] = pk;
            }
        }

        #pragma unroll
        for (int ks = 0; ks < 2; ks++) {
            const int pr = wq0 + fcol;
            bf16x8 ap = *(const bf16x8*)&QPs[pr * 64 + (((ks * 4 + quad) ^ (pr & 7)) * 8)];
            lacc = __builtin_amdgcn_mfma_f32_16x16x32_bf16(ap, bones, lacc, 0, 0, 0);
            #pragma unroll
            for (int jd = 0; jd < 4; jd++) {
                const int vr = jd * 16 + fcol;
                bf16x8 bv = *(const bf16x8*)&Vts[cur][vr * 64 + (((ks * 4 + quad) ^ (vr & 7)) * 8)];
                oacc[jd] = __builtin_amdgcn_mfma_f32_16x16x32_bf16(ap, bv, oacc[jd], 0, 0, 0);
            }
        }
    }

    #pragma unroll
    for (int r = 0; r < 4; r++) {
        const float inv = 1.0f / lacc[r];
        const size_t row = (size_t)(b * NT + q0 + wq0 + quad * 4 + r);
        #pragma unroll
        for (int jd = 0; jd < 4; jd++)
            out[row * ND + h * HD + jd * 16 + fcol] = f2bf(oacc[jd][r] * inv);
    }
}

extern "C" void kernel_launch(void* const* d_in, const int* in_sizes, int n_in,
                              void* d_out, int out_size, void* d_ws, size_t ws_size,
                              hipStream_t stream) {
    const float* x        = (const float*)d_in[0];
    const int*   amask    = (const int*)  d_in[1];
    const float* ln1_w    = (const float*)d_in[2];
    const float* ln1_b    = (const float*)d_in[3];
    const float* w_attn   = (const float*)d_in[4];
    const float* b_attn   = (const float*)d_in[5];
    const float* w_proj   = (const float*)d_in[6];
    const float* b_proj   = (const float*)d_in[7];
    const float* ln2_w    = (const float*)d_in[8];
    const float* ln2_b    = (const float*)d_in[9];
    const float* w_fc     = (const float*)d_in[10];
    const float* b_fc     = (const float*)d_in[11];
    const float* w_fcp    = (const float*)d_in[12];
    const float* b_fcp    = (const float*)d_in[13];
    float* out = (float*)d_out;

    ushort_t* ws = (ushort_t*)d_ws;
    ushort_t* qkvb   = ws;                               // BT*3*ND
    ushort_t* x1b    = qkvb + (size_t)BT * 3 * ND;       // BT*ND
    ushort_t* attn_b = x1b + (size_t)BT * ND;            // BT*ND
    ushort_t* hbuf   = attn_b + (size_t)BT * ND;         // BT*4*ND
    ushort_t* vTb    = hbuf + (size_t)BT * 4 * ND;       // BT*ND
    ushort_t* wA_T   = vTb + (size_t)BT * ND;            // 2304*768
    ushort_t* wP_T   = wA_T + (size_t)2304 * 768;        // 768*768
    ushort_t* wF_T   = wP_T + (size_t)768 * 768;         // 3072*768
    ushort_t* wFP_T  = wF_T + (size_t)3072 * 768;        // 768*3072

    transpose_all<<<6912, 256, 0, stream>>>(w_attn, wA_T, w_proj, wP_T, w_fc, wF_T, w_fcp, wFP_T);

    ln_kernel<<<BT / 4, 256, 0, stream>>>(x, ln1_w, ln1_b, x1b);
    gemm128n<0, 2304, 768><<<dim3(2304 / 256, BT / 128), 512, 0, stream>>>(x1b, wA_T, b_attn, qkvb);
    transpose_v<<<dim3(16, NH, NB), 256, 0, stream>>>(qkvb, vTb);
    flash_attn_mfma<<<dim3(16, NH, NB), 256, 0, stream>>>(qkvb, vTb, amask, attn_b);
    gemm_bt<1><<<dim3(768 / 128, BT / 128), 256, 0, stream>>>(attn_b, wP_T, b_proj, x, out, BT, ND, ND);
    ln_kernel<<<BT / 4, 256, 0, stream>>>(out, ln2_w, ln2_b, x1b);
    gemm128n<2, 3072, 768><<<dim3(3072 / 256, BT / 128), 512, 0, stream>>>(x1b, wF_T, b_fc, hbuf);
    gemm_bt<1><<<dim3(768 / 128, BT / 128), 256, 0, stream>>>(hbuf, wFP_T, b_fcp, out, out, BT, ND, 4 * ND);
}

// Round 9
// 350.400 us; speedup vs baseline: 1.0230x; 1.0230x over previous
//
#include <hip/hip_runtime.h>
#include <hip/hip_bf16.h>
#include <math.h>

#define NB 8
#define NT 1024
#define ND 768
#define NH 12
#define HD 64
#define WINDOW 768
#define LN_EPS 1e-5f
#define NEGF -3.4028234663852886e38f
#define SCL2 0.18033688011112042f   // 0.125 * log2(e)

static const int BT = NB * NT;  // 8192 rows

typedef __bf16 bf16x8 __attribute__((ext_vector_type(8)));
typedef float  f32x4  __attribute__((ext_vector_type(4)));
typedef unsigned short ushort_t;

__device__ __forceinline__ unsigned short f2bf(float f) {
    __hip_bfloat16 h = __float2bfloat16(f);
    return __builtin_bit_cast(unsigned short, h);
}

// async global->LDS, 16B per lane. LDS dest = wave-uniform base + lane*16.
__device__ __forceinline__ void load_lds16(const void* g, void* l) {
    __builtin_amdgcn_global_load_lds((const __attribute__((address_space(1))) unsigned int*)g,
                                     (__attribute__((address_space(3))) unsigned int*)l,
                                     16, 0, 0);
}

// inline-asm ds_read_b128 with compile-time offset immediate: ONE base VGPR serves
// all fragment reads of a class (slot + subtile folded into offset:IMM).
template <int IMM>
__device__ __forceinline__ bf16x8 ds_read16o(unsigned base) {
    bf16x8 r;
    asm volatile("ds_read_b128 %0, %1 offset:%2" : "=v"(r) : "v"(base), "n"(IMM));
    return r;
}

// ---------------- all weight transposes fused: wT[n][k] = bf16(w[k][n]) --------
__global__ __launch_bounds__(256) void transpose_all(const float* __restrict__ w0, ushort_t* __restrict__ t0v,
                                                     const float* __restrict__ w1, ushort_t* __restrict__ t1v,
                                                     const float* __restrict__ w2, ushort_t* __restrict__ t2v,
                                                     const float* __restrict__ w3, ushort_t* __restrict__ t3v) {
    int bid = blockIdx.x;
    const float* w; ushort_t* wt; int K, N;
    if (bid < 1728)                    { w = w0; wt = t0v; K = 768;  N = 2304; }
    else if ((bid -= 1728) < 576)      { w = w1; wt = t1v; K = 768;  N = 768;  }
    else if ((bid -= 576) < 2304)      { w = w2; wt = t2v; K = 768;  N = 3072; }
    else       { bid -= 2304;            w = w3; wt = t3v; K = 3072; N = 768;  }
    const int nxt = N / 32;
    const int n0 = (bid % nxt) * 32, k0 = (bid / nxt) * 32;
    __shared__ float t[32][33];
    const int tx = threadIdx.x & 31, ty = threadIdx.x >> 5;  // 32 x 8
    for (int r = ty; r < 32; r += 8)
        t[r][tx] = w[(size_t)(k0 + r) * N + n0 + tx];
    __syncthreads();
    for (int r = ty; r < 32; r += 8)
        wt[(size_t)(n0 + r) * K + k0 + tx] = f2bf(t[tx][r]);
}

// ---------------- V transpose (pi-permuted keys): vT[b][h][d][t'] --------------
__global__ __launch_bounds__(256) void transpose_v(const ushort_t* __restrict__ qkvb,
                                                   ushort_t* __restrict__ vT) {
    const int t0 = blockIdx.x * 64;
    const int h = blockIdx.y, b = blockIdx.z;
    __shared__ ushort_t sm[64 * 72];
    const int tid = threadIdx.x;
    #pragma unroll
    for (int p = 0; p < 2; p++) {
        int idx = p * 256 + tid;
        int r = idx >> 3, c = idx & 7;
        *(bf16x8*)&sm[r * 72 + c * 8] =
            *(const bf16x8*)(qkvb + (size_t)(b * NT + t0 + r) * (3 * ND) + 2 * ND + h * HD + c * 8);
    }
    __syncthreads();
    #pragma unroll
    for (int p = 0; p < 2; p++) {
        int idx = p * 256 + tid;
        int d = idx >> 3, c2 = idx & 7;
        ushort_t tmp[8];
        #pragma unroll
        for (int j = 0; j < 8; j++) {
            int kp = c2 * 8 + j;
            int key = ((kp & 1) << 4) | ((kp >> 1) & 15) | (kp & 32);
            tmp[j] = sm[key * 72 + d];
        }
        *(bf16x8*)(vT + ((size_t)((b * NH + h) * HD + d)) * NT + t0 + c2 * 8) = *(bf16x8*)tmp;
    }
}

// ---------------- LayerNorm -> bf16: wave-per-row, shuffle reduce --------------
__global__ __launch_bounds__(256) void ln_kernel(const float* __restrict__ x,
                                                 const float* __restrict__ w,
                                                 const float* __restrict__ b,
                                                 ushort_t* __restrict__ out) {
    const int row  = blockIdx.x * 4 + (threadIdx.x >> 6);
    const int lane = threadIdx.x & 63;
    const float* xr = x + (size_t)row * ND;

    float4 v[3];
    #pragma unroll
    for (int s = 0; s < 3; s++) v[s] = *(const float4*)(xr + s * 256 + lane * 4);

    float sum = 0.f;
    #pragma unroll
    for (int s = 0; s < 3; s++) sum += v[s].x + v[s].y + v[s].z + v[s].w;
    #pragma unroll
    for (int off = 1; off < 64; off <<= 1) sum += __shfl_xor(sum, off, 64);
    const float mu = sum * (1.0f / ND);

    float var = 0.f;
    #pragma unroll
    for (int s = 0; s < 3; s++) {
        float a0 = v[s].x - mu, a1 = v[s].y - mu, a2 = v[s].z - mu, a3 = v[s].w - mu;
        var += a0 * a0 + a1 * a1 + a2 * a2 + a3 * a3;
    }
    #pragma unroll
    for (int off = 1; off < 64; off <<= 1) var += __shfl_xor(var, off, 64);
    const float rstd = rsqrtf(var * (1.0f / ND) + LN_EPS);

    #pragma unroll
    for (int s = 0; s < 3; s++) {
        const int col = s * 256 + lane * 4;
        float4 w4 = *(const float4*)(w + col);
        float4 b4 = *(const float4*)(b + col);
        ushort4 r;
        r.x = f2bf((v[s].x - mu) * rstd * w4.x + b4.x);
        r.y = f2bf((v[s].y - mu) * rstd * w4.y + b4.y);
        r.z = f2bf((v[s].z - mu) * rstd * w4.z + b4.z);
        r.w = f2bf((v[s].w - mu) * rstd * w4.w + b4.w);
        *(ushort4*)(out + (size_t)row * ND + col) = r;
    }
}

// ---------------- bf16 MFMA GEMM, double-buffered pipeline (128x128) -----------
// Kept for the two N=768 GEMMs, bijective XCD-chunk swizzle (grids %8==0).
// Round-9: row-pair LDS swizzle (8-way -> 2-way; 4.7M SQ_LDS_BANK_CONFLICT seen
// on the K=3072 dispatch). phys(r,c) = (r>>1)*128B + ((((r&1)<<2)|c)^((r>>1)&7))*16B;
// inverse applied on the GLOBAL source (linear LDS dest, rule #21); frag-read rows
// are 16-multiple + fcol so (pair&7) == fcol>>1, lane-uniform.
// EPI: 1 = +bias+resid -> fp32
template <int EPI>
__global__ __launch_bounds__(256) void gemm_bt(const ushort_t* __restrict__ A,
                                               const ushort_t* __restrict__ Bt,
                                               const float* __restrict__ bias,
                                               const float* __restrict__ resid,
                                               void* __restrict__ Cout,
                                               int M, int N, int K) {
    __shared__ __align__(16) ushort_t smem[2][2][128 * 32];  // [buf][A/B][...]

    const int tid  = threadIdx.x;
    const int nwg   = gridDim.x * gridDim.y;
    const int flatb = blockIdx.y * gridDim.x + blockIdx.x;
    const int q8    = nwg >> 3;
    const int swz   = (flatb & 7) * q8 + (flatb >> 3);
    const int bm   = (swz / gridDim.x) * 128;
    const int bn   = (swz % gridDim.x) * 128;
    const int lane = tid & 63;
    const int wave = tid >> 6;
    const int wm   = (wave & 1) * 64;
    const int wn   = (wave >> 1) * 64;
    const int fcol = lane & 15;
    const int quad = lane >> 4;

    f32x4 acc[4][4] = {};

    auto issue = [&](int k0, int buf) {
        #pragma unroll
        for (int p = 0; p < 2; p++) {
            const int f = p * 256 + tid;            // [0,512): 128 rows x 4 chunks
            const int pr = f >> 3, s2 = (f & 7) ^ (pr & 7);
            const int r = pr * 2 + (s2 >> 2), c = s2 & 3;
            load_lds16(A  + (size_t)(bm + r) * K + k0 + c * 8, &smem[buf][0][f * 8]);
            load_lds16(Bt + (size_t)(bn + r) * K + k0 + c * 8, &smem[buf][1][f * 8]);
        }
    };

    // frag-read swizzle term: slot = (((fcol&1)<<2)|quad) ^ (fcol>>1)
    const int slr = ((((fcol & 1) << 2) | quad) ^ (fcol >> 1)) * 8;

    issue(0, 0);
    const int KT = K >> 5;
    for (int kt = 0; kt < KT; kt++) {
        const int cur = kt & 1;
        __syncthreads();
        if (kt + 1 < KT) issue((kt + 1) << 5, cur ^ 1);

        bf16x8 a[4], b[4];
        #pragma unroll
        for (int i = 0; i < 4; i++)
            a[i] = *(const bf16x8*)&smem[cur][0][((wm + i * 16 + fcol) >> 1) * 64 + slr];
        #pragma unroll
        for (int j = 0; j < 4; j++)
            b[j] = *(const bf16x8*)&smem[cur][1][((wn + j * 16 + fcol) >> 1) * 64 + slr];
        #pragma unroll
        for (int i = 0; i < 4; i++)
            #pragma unroll
            for (int j = 0; j < 4; j++)
                acc[i][j] = __builtin_amdgcn_mfma_f32_16x16x32_bf16(a[i], b[j], acc[i][j], 0, 0, 0);
    }

    if (EPI == 1) {
        #pragma unroll
        for (int j = 0; j < 4; j++) {
            const int gcol = bn + wn + j * 16 + fcol;
            const float bs = bias[gcol];
            #pragma unroll
            for (int i = 0; i < 4; i++) {
                #pragma unroll
                for (int r = 0; r < 4; r++) {
                    const int grow = bm + wm + i * 16 + quad * 4 + r;
                    float val = acc[i][j][r] + bs + resid[(size_t)grow * N + gcol];
                    ((float*)Cout)[(size_t)grow * N + gcol] = val;
                }
            }
        }
    } else {
        __syncthreads();
        ushort_t* Cs = &smem[0][0][0] + wave * (64 * 40);
        #pragma unroll
        for (int hh = 0; hh < 2; hh++) {
            #pragma unroll
            for (int jj = 0; jj < 2; jj++) {
                const int j = hh * 2 + jj;
                const float bs = bias[bn + wn + j * 16 + fcol];
                #pragma unroll
                for (int i = 0; i < 4; i++) {
                    #pragma unroll
                    for (int r = 0; r < 4; r++) {
                        float val = acc[i][j][r] + bs;
                        if (EPI == 2) {
                            float y = 0.7978845608028654f * (val + 0.044715f * val * val * val);
                            float t = 1.0f - 2.0f / (1.0f + __expf(2.0f * y));
                            val = 0.5f * val * (1.0f + t);
                        }
                        const int lr = i * 16 + quad * 4 + r;
                        Cs[lr * 40 + jj * 16 + fcol] = f2bf(val);
                    }
                }
            }
            #pragma unroll
            for (int p = 0; p < 4; p++) {
                const int cid = p * 64 + lane;
                const int lr = cid >> 2, ck = cid & 3;
                bf16x8 vv = *(const bf16x8*)&Cs[lr * 40 + ck * 8];
                *(bf16x8*)((ushort_t*)Cout + (size_t)(bm + wm + lr) * N + bn + wn + hh * 32 + ck * 8) = vv;
            }
        }
    }
}

// ---------------- 128x256 BK=32 GEMM: 3-deep prefetch + 2 blocks/CU ------------
// Round-8 kernel (verified; conflicts 196K) with ONE change: 2-slot -> 3-SLOT
// staging ring. Round-8 showed the VMW wait, not LDS reads, is the stall: load->
// use distance was 1 iteration (~450 cy) vs ~200-900 cy HBM/L2 latency. 3 slots
// give distance 2 iterations (~1000 cy) -> latency covered. LDS 48->72 KB still
// allows 2 blocks/CU (144 <= 160 KB).
// Ledger: prologue stages {0,1,2} = 9 outstanding, VMW(6) -> tile0 landed.
// Steady state (unroll-by-3, slot = tile%3 compile-time): after BARR (all waves
// done reading slot s), stage(t+3 -> slot s) -> 9 outstanding; VMW(6) -> t+1
// landed, {t+2,t+3} in flight; BARR publishes. Tail stages clamp kk (dummy).
// EPI: 0 = +bias -> bf16;  2 = +bias,gelu(tanh) -> bf16
template <int EPI, int NN, int KK>
__global__ __launch_bounds__(512, 4) void gemm128n(const ushort_t* __restrict__ A,
                                                   const ushort_t* __restrict__ Bt,
                                                   const float* __restrict__ bias,
                                                   ushort_t* __restrict__ Cout) {
    __shared__ __align__(16) ushort_t lds[36864];   // 72 KB: A 3x4096, B 3x8192 ushorts

    const int tid  = threadIdx.x;
    const int lane = tid & 63;
    const int wave = tid >> 6;     // 0..7
    const int wr   = wave >> 2;    // 0..1  (64-row half)
    const int wn   = wave & 3;     // 0..3  (64-col quarter)
    const int fcol = lane & 15;
    const int quad = lane >> 4;

    // bijective XCD-chunk swizzle (nwg = 576 / 768, both % 8 == 0)
    const int nwg   = gridDim.x * gridDim.y;
    const int flatb = blockIdx.y * gridDim.x + blockIdx.x;
    const int q8    = nwg >> 3;
    const int swz   = (flatb & 7) * q8 + (flatb >> 3);
    const int bm    = (swz / gridDim.x) * 128;
    const int bn    = (swz % gridDim.x) * 256;

    constexpr int KTILES = KK >> 5;   // 32-wide K tiles (24 for K=768)

    f32x4 acc[4][4] = {};             // 64 regs: wave's 64x64 output
    bf16x8 ra[4], rbv[4];

    // fragment-read bases (row-pair swizzle, verified round 8): pair&7 == fcol>>1
    const unsigned ldsb = (unsigned)(size_t)(const __attribute__((address_space(3))) ushort_t*)lds;
    const unsigned slotr = (unsigned)(((((fcol & 1) << 2) | quad) ^ (fcol >> 1)) * 16);
    const unsigned baseA = ldsb + (unsigned)((wr * 32 + (fcol >> 1)) * 128) + slotr;
    const unsigned baseB = ldsb + 24576u + (unsigned)((wn * 32 + (fcol >> 1)) * 128) + slotr;

    auto stage = [&](int kt, int slot) {   // exactly 3 global_load_lds per thread
        const int kk = (kt < KTILES ? kt : 0) << 5;   // clamp keeps vmcnt ledger
        ushort_t* dstA = lds + slot * 4096;
        {
            const int f = tid;                         // 512 loads cover 128x32
            const int pr = f >> 3, s2 = (f & 7) ^ (pr & 7);
            const int r = pr * 2 + (s2 >> 2), c = s2 & 3;
            load_lds16(A + (size_t)(bm + r) * KK + kk + c * 8, dstA + f * 8);
        }
        ushort_t* dstB = lds + 12288 + slot * 8192;
        #pragma unroll
        for (int p = 0; p < 2; p++) {                  // 1024 loads cover 256x32
            const int f = (p << 9) + tid;
            const int pr = f >> 3, s2 = (f & 7) ^ (pr & 7);
            const int r = pr * 2 + (s2 >> 2), c = s2 & 3;
            load_lds16(Bt + (size_t)(bn + r) * KK + kk + c * 8, dstB + f * 8);
        }
    };

#define RD_T(CUR) {                                                        \
    ra[0]  = ds_read16o<(CUR) * 8192 + 0   >(baseA);                       \
    ra[1]  = ds_read16o<(CUR) * 8192 + 1024>(baseA);                       \
    ra[2]  = ds_read16o<(CUR) * 8192 + 2048>(baseA);                       \
    ra[3]  = ds_read16o<(CUR) * 8192 + 3072>(baseA);                       \
    rbv[0] = ds_read16o<(CUR) * 16384 + 0   >(baseB);                      \
    rbv[1] = ds_read16o<(CUR) * 16384 + 1024>(baseB);                      \
    rbv[2] = ds_read16o<(CUR) * 16384 + 2048>(baseB);                      \
    rbv[3] = ds_read16o<(CUR) * 16384 + 3072>(baseB); }
#define LGKM0() { asm volatile("s_waitcnt lgkmcnt(0)" ::: "memory");       \
    __builtin_amdgcn_sched_barrier(0); }
#define MMA16() {                                                          \
    __builtin_amdgcn_s_setprio(1);                                         \
    _Pragma("unroll") for (int i = 0; i < 4; i++)                          \
    _Pragma("unroll") for (int j = 0; j < 4; j++)                          \
        acc[i][j] = __builtin_amdgcn_mfma_f32_16x16x32_bf16(               \
            ra[i], rbv[j], acc[i][j], 0, 0, 0);                            \
    __builtin_amdgcn_s_setprio(0);                                         \
    __builtin_amdgcn_sched_barrier(0); }
#define VMW6() asm volatile("s_waitcnt vmcnt(6)" ::: "memory")
#define BARR() asm volatile("s_barrier" ::: "memory")

    stage(0, 0); stage(1, 1); stage(2, 2);
    VMW6();                       // tile0's 3 oldest loads landed
    BARR();

    #pragma unroll 1
    for (int it = 0; it < KTILES / 3; ++it) {
        const int t = it * 3;
        // tile t -> slot 0
        RD_T(0);
        LGKM0();
        MMA16();
        BARR();                   // all waves done reading slot 0
        stage(t + 3, 0);          // overwrite slot 0 (WAR-safe)
        VMW6();                   // tile t+1 landed (own-wave)
        BARR();                   // publish block-wide
        // tile t+1 -> slot 1
        RD_T(1);
        LGKM0();
        MMA16();
        BARR();
        stage(t + 4, 1);
        VMW6();
        BARR();
        // tile t+2 -> slot 2
        RD_T(2);
        LGKM0();
        MMA16();
        BARR();
        stage(t + 5, 2);
        VMW6();
        BARR();
    }

    // full drain before LDS reuse
    asm volatile("s_waitcnt vmcnt(0) lgkmcnt(0)" ::: "memory");
    BARR();

    // epilogue: per-wave 32-row LDS staging (32x72 per wave = 36 KB total)
    ushort_t* Cs = lds + wave * (32 * 72);
    #pragma unroll
    for (int h = 0; h < 2; h++) {
        #pragma unroll
        for (int j = 0; j < 4; j++) {
            const float bs = bias[bn + wn * 64 + j * 16 + fcol];
            #pragma unroll
            for (int i2 = 0; i2 < 2; i2++) {
                #pragma unroll
                for (int r = 0; r < 4; r++) {
                    float val = acc[h * 2 + i2][j][r] + bs;
                    if (EPI == 2) {
                        float y = 0.7978845608028654f * (val + 0.044715f * val * val * val);
                        float t = 1.0f - 2.0f / (1.0f + __expf(2.0f * y));
                        val = 0.5f * val * (1.0f + t);
                    }
                    Cs[(i2 * 16 + quad * 4 + r) * 72 + j * 16 + fcol] = f2bf(val);
                }
            }
        }
        __builtin_amdgcn_sched_barrier(0);   // order within-wave store->load
        #pragma unroll
        for (int p = 0; p < 4; p++) {
            const int cid = (p << 6) + lane;
            const int lr = cid >> 3, ck = cid & 7;
            bf16x8 vv = *(const bf16x8*)&Cs[lr * 72 + ck * 8];
            *(bf16x8*)(Cout + (size_t)(bm + wr * 64 + h * 32 + lr) * NN + bn + wn * 64 + ck * 8) = vv;
        }
        __builtin_amdgcn_sched_barrier(0);
    }
#undef RD_T
#undef LGKM0
#undef MMA16
#undef VMW6
#undef BARR
}

// ---------------- MFMA flash attention: no-max softmax, l via ones-MFMA --------
__global__ __launch_bounds__(256) void flash_attn_mfma(const ushort_t* __restrict__ qkvb,
                                                       const ushort_t* __restrict__ vT,
                                                       const int* __restrict__ amask,
                                                       ushort_t* __restrict__ out) {
    const int qt = 15 - blockIdx.x;   // heavy tiles first
    const int h  = blockIdx.y;
    const int b  = blockIdx.z;
    const int q0 = qt * 64;

    __shared__ __align__(16) ushort_t QPs[64 * 64];      // Q, then reused for P
    __shared__ __align__(16) ushort_t Ks[2][64 * 64];
    __shared__ __align__(16) ushort_t Vts[2][64 * 64];

    const int tid  = threadIdx.x;
    const int lane = tid & 63;
    const int wave = tid >> 6;
    const int fcol = lane & 15;
    const int quad = lane >> 4;
    const int wq0  = wave * 16;

    #pragma unroll
    for (int p = 0; p < 2; p++) {
        int flat = p * 256 + tid;
        int r = flat >> 3, c = (flat & 7) ^ (r & 7);
        load_lds16(qkvb + (size_t)(b * NT + q0 + r) * (3 * ND) + h * HD + c * 8, &QPs[flat * 8]);
    }
    __syncthreads();

    bf16x8 aQ[2];
    {
        const int qr = wq0 + fcol;
        #pragma unroll
        for (int ks = 0; ks < 2; ks++) {
            int c = ks * 4 + quad;
            aQ[ks] = *(const bf16x8*)&QPs[qr * 64 + ((c ^ (qr & 7)) * 8)];
        }
    }

    bf16x8 bones;
    #pragma unroll
    for (int i = 0; i < 8; i++) bones[i] = (__bf16)1.0f;

    auto issueKV = [&](int cch, int buf) {
        const int kbase = cch * 64;
        #pragma unroll
        for (int p = 0; p < 2; p++) {
            int flat = p * 256 + tid;
            int r = flat >> 3, c = (flat & 7) ^ (r & 7);
            load_lds16(qkvb + (size_t)(b * NT + kbase + r) * (3 * ND) + ND + h * HD + c * 8,
                       &Ks[buf][flat * 8]);
            load_lds16(vT + ((size_t)((b * NH + h) * HD + r)) * NT + kbase + c * 8,
                       &Vts[buf][flat * 8]);
        }
    };

    f32x4 oacc[4] = {};
    f32x4 lacc = {};

    const int c_lo = (qt > 12) ? (qt - 12) : 0;
    issueKV(c_lo, 0);
    for (int cch = c_lo; cch <= qt; cch++) {
        const int cur = (cch - c_lo) & 1;
        const int kbase = cch * 64;
        __syncthreads();
        if (cch + 1 <= qt) issueKV(cch + 1, cur ^ 1);

        int am[4];
        #pragma unroll
        for (int jn = 0; jn < 4; jn++) am[jn] = amask[b * NT + kbase + jn * 16 + fcol];
        const int amok_lane = (am[0] != 0) & (am[1] != 0) & (am[2] != 0) & (am[3] != 0);
        const bool fast = (cch < qt) && (cch >= qt - 11) && __all(amok_lane);

        f32x4 sc[4] = {};
        #pragma unroll
        for (int ks = 0; ks < 2; ks++) {
            #pragma unroll
            for (int jn = 0; jn < 4; jn++) {
                const int kr = jn * 16 + fcol;
                bf16x8 bk = *(const bf16x8*)&Ks[cur][kr * 64 + (((ks * 4 + quad) ^ (kr & 7)) * 8)];
                sc[jn] = __builtin_amdgcn_mfma_f32_16x16x32_bf16(aQ[ks], bk, sc[jn], 0, 0, 0);
            }
        }

        float pvv[4][4];
        if (fast) {
            #pragma unroll
            for (int jn = 0; jn < 4; jn++)
                #pragma unroll
                for (int r = 0; r < 4; r++)
                    pvv[jn][r] = __builtin_amdgcn_exp2f(sc[jn][r] * SCL2);
        } else {
            #pragma unroll
            for (int jn = 0; jn < 4; jn++) {
                const int jg = kbase + jn * 16 + fcol;
                const bool amok = (am[jn] != 0);
                #pragma unroll
                for (int r = 0; r < 4; r++) {
                    const int ig = q0 + wq0 + quad * 4 + r;
                    bool keep = (jg <= ig) && (jg >= ig - (WINDOW - 1)) && amok;
                    float s = keep ? sc[jn][r] * SCL2 : -1e38f;
                    pvv[jn][r] = __builtin_amdgcn_exp2f(s);
                }
            }
        }

        #pragma unroll
        for (int half = 0; half < 2; half++) {
            const int cbase = half * 4 + (fcol >> 2);
            const int off = (fcol & 3) * 2;
            #pragma unroll
            for (int r = 0; r < 4; r++) {
                const int row = wq0 + quad * 4 + r;
                unsigned int pk = (unsigned int)f2bf(pvv[half * 2][r]) |
                                  ((unsigned int)f2bf(pvv[half * 2 + 1][r]) << 16);
                *(unsigned int*)&QPs[row * 64 + ((cbase ^ (row & 7)) * 8) + off] = pk;
            }
        }

        #pragma unroll
        for (int ks = 0; ks < 2; ks++) {
            const int pr = wq0 + fcol;
            bf16x8 ap = *(const bf16x8*)&QPs[pr * 64 + (((ks * 4 + quad) ^ (pr & 7)) * 8)];
            lacc = __builtin_amdgcn_mfma_f32_16x16x32_bf16(ap, bones, lacc, 0, 0, 0);
            #pragma unroll
            for (int jd = 0; jd < 4; jd++) {
                const int vr = jd * 16 + fcol;
                bf16x8 bv = *(const bf16x8*)&Vts[cur][vr * 64 + (((ks * 4 + quad) ^ (vr & 7)) * 8)];
                oacc[jd] = __builtin_amdgcn_mfma_f32_16x16x32_bf16(ap, bv, oacc[jd], 0, 0, 0);
            }
        }
    }

    #pragma unroll
    for (int r = 0; r < 4; r++) {
        const float inv = 1.0f / lacc[r];
        const size_t row = (size_t)(b * NT + q0 + wq0 + quad * 4 + r);
        #pragma unroll
        for (int jd = 0; jd < 4; jd++)
            out[row * ND + h * HD + jd * 16 + fcol] = f2bf(oacc[jd][r] * inv);
    }
}

extern "C" void kernel_launch(void* const* d_in, const int* in_sizes, int n_in,
                              void* d_out, int out_size, void* d_ws, size_t ws_size,
                              hipStream_t stream) {
    const float* x        = (const float*)d_in[0];
    const int*   amask    = (const int*)  d_in[1];
    const float* ln1_w    = (const float*)d_in[2];
    const float* ln1_b    = (const float*)d_in[3];
    const float* w_attn   = (const float*)d_in[4];
    const float* b_attn   = (const float*)d_in[5];
    const float* w_proj   = (const float*)d_in[6];
    const float* b_proj   = (const float*)d_in[7];
    const float* ln2_w    = (const float*)d_in[8];
    const float* ln2_b    = (const float*)d_in[9];
    const float* w_fc     = (const float*)d_in[10];
    const float* b_fc     = (const float*)d_in[11];
    const float* w_fcp    = (const float*)d_in[12];
    const float* b_fcp    = (const float*)d_in[13];
    float* out = (float*)d_out;

    ushort_t* ws = (ushort_t*)d_ws;
    ushort_t* qkvb   = ws;                               // BT*3*ND
    ushort_t* x1b    = qkvb + (size_t)BT * 3 * ND;       // BT*ND
    ushort_t* attn_b = x1b + (size_t)BT * ND;            // BT*ND
    ushort_t* hbuf   = attn_b + (size_t)BT * ND;         // BT*4*ND
    ushort_t* vTb    = hbuf + (size_t)BT * 4 * ND;       // BT*ND
    ushort_t* wA_T   = vTb + (size_t)BT * ND;            // 2304*768
    ushort_t* wP_T   = wA_T + (size_t)2304 * 768;        // 768*768
    ushort_t* wF_T   = wP_T + (size_t)768 * 768;         // 3072*768
    ushort_t* wFP_T  = wF_T + (size_t)3072 * 768;        // 768*3072

    transpose_all<<<6912, 256, 0, stream>>>(w_attn, wA_T, w_proj, wP_T, w_fc, wF_T, w_fcp, wFP_T);

    ln_kernel<<<BT / 4, 256, 0, stream>>>(x, ln1_w, ln1_b, x1b);
    gemm128n<0, 2304, 768><<<dim3(2304 / 256, BT / 128), 512, 0, stream>>>(x1b, wA_T, b_attn, qkvb);
    transpose_v<<<dim3(16, NH, NB), 256, 0, stream>>>(qkvb, vTb);
    flash_attn_mfma<<<dim3(16, NH, NB), 256, 0, stream>>>(qkvb, vTb, amask, attn_b);
    gemm_bt<1><<<dim3(768 / 128, BT / 128), 256, 0, stream>>>(attn_b, wP_T, b_proj, x, out, BT, ND, ND);
    ln_kernel<<<BT / 4, 256, 0, stream>>>(out, ln2_w, ln2_b, x1b);
    gemm128n<2, 3072, 768><<<dim3(3072 / 256, BT / 128), 512, 0, stream>>>(x1b, wF_T, b_fc, hbuf);
    gemm_bt<1><<<dim3(768 / 128, BT / 128), 256, 0, stream>>>(hbuf, wFP_T, b_fcp, out, out, BT, ND, 4 * ND);
}

// Round 10
// 350.375 us; speedup vs baseline: 1.0231x; 1.0001x over previous
//
#include <hip/hip_runtime.h>
#include <hip/hip_bf16.h>
#include <math.h>

#define NB 8
#define NT 1024
#define ND 768
#define NH 12
#define HD 64
#define WINDOW 768
#define LN_EPS 1e-5f
#define NEGF -3.4028234663852886e38f
#define SCL2 0.18033688011112042f   // 0.125 * log2(e)

static const int BT = NB * NT;  // 8192 rows

typedef __bf16 bf16x8 __attribute__((ext_vector_type(8)));
typedef float  f32x4  __attribute__((ext_vector_type(4)));
typedef unsigned short ushort_t;

__device__ __forceinline__ unsigned short f2bf(float f) {
    __hip_bfloat16 h = __float2bfloat16(f);
    return __builtin_bit_cast(unsigned short, h);
}

// async global->LDS, 16B per lane. LDS dest = wave-uniform base + lane*16.
__device__ __forceinline__ void load_lds16(const void* g, void* l) {
    __builtin_amdgcn_global_load_lds((const __attribute__((address_space(1))) unsigned int*)g,
                                     (__attribute__((address_space(3))) unsigned int*)l,
                                     16, 0, 0);
}

// inline-asm ds_read_b128 with compile-time offset immediate: ONE base VGPR serves
// all fragment reads of a class (slot + subtile folded into offset:IMM).
template <int IMM>
__device__ __forceinline__ bf16x8 ds_read16o(unsigned base) {
    bf16x8 r;
    asm volatile("ds_read_b128 %0, %1 offset:%2" : "=v"(r) : "v"(base), "n"(IMM));
    return r;
}

// ---------------- all weight transposes fused: wT[n][k] = bf16(w[k][n]) --------
__global__ __launch_bounds__(256) void transpose_all(const float* __restrict__ w0, ushort_t* __restrict__ t0v,
                                                     const float* __restrict__ w1, ushort_t* __restrict__ t1v,
                                                     const float* __restrict__ w2, ushort_t* __restrict__ t2v,
                                                     const float* __restrict__ w3, ushort_t* __restrict__ t3v) {
    int bid = blockIdx.x;
    const float* w; ushort_t* wt; int K, N;
    if (bid < 1728)                    { w = w0; wt = t0v; K = 768;  N = 2304; }
    else if ((bid -= 1728) < 576)      { w = w1; wt = t1v; K = 768;  N = 768;  }
    else if ((bid -= 576) < 2304)      { w = w2; wt = t2v; K = 768;  N = 3072; }
    else       { bid -= 2304;            w = w3; wt = t3v; K = 3072; N = 768;  }
    const int nxt = N / 32;
    const int n0 = (bid % nxt) * 32, k0 = (bid / nxt) * 32;
    __shared__ float t[32][33];
    const int tx = threadIdx.x & 31, ty = threadIdx.x >> 5;  // 32 x 8
    for (int r = ty; r < 32; r += 8)
        t[r][tx] = w[(size_t)(k0 + r) * N + n0 + tx];
    __syncthreads();
    for (int r = ty; r < 32; r += 8)
        wt[(size_t)(n0 + r) * K + k0 + tx] = f2bf(t[tx][r]);
}

// ---------------- V transpose (pi-permuted keys): vT[b][h][d][t'] --------------
__global__ __launch_bounds__(256) void transpose_v(const ushort_t* __restrict__ qkvb,
                                                   ushort_t* __restrict__ vT) {
    const int t0 = blockIdx.x * 64;
    const int h = blockIdx.y, b = blockIdx.z;
    __shared__ ushort_t sm[64 * 72];
    const int tid = threadIdx.x;
    #pragma unroll
    for (int p = 0; p < 2; p++) {
        int idx = p * 256 + tid;
        int r = idx >> 3, c = idx & 7;
        *(bf16x8*)&sm[r * 72 + c * 8] =
            *(const bf16x8*)(qkvb + (size_t)(b * NT + t0 + r) * (3 * ND) + 2 * ND + h * HD + c * 8);
    }
    __syncthreads();
    #pragma unroll
    for (int p = 0; p < 2; p++) {
        int idx = p * 256 + tid;
        int d = idx >> 3, c2 = idx & 7;
        ushort_t tmp[8];
        #pragma unroll
        for (int j = 0; j < 8; j++) {
            int kp = c2 * 8 + j;
            int key = ((kp & 1) << 4) | ((kp >> 1) & 15) | (kp & 32);
            tmp[j] = sm[key * 72 + d];
        }
        *(bf16x8*)(vT + ((size_t)((b * NH + h) * HD + d)) * NT + t0 + c2 * 8) = *(bf16x8*)tmp;
    }
}

// ---------------- LayerNorm -> bf16: wave-per-row, shuffle reduce --------------
__global__ __launch_bounds__(256) void ln_kernel(const float* __restrict__ x,
                                                 const float* __restrict__ w,
                                                 const float* __restrict__ b,
                                                 ushort_t* __restrict__ out) {
    const int row  = blockIdx.x * 4 + (threadIdx.x >> 6);
    const int lane = threadIdx.x & 63;
    const float* xr = x + (size_t)row * ND;

    float4 v[3];
    #pragma unroll
    for (int s = 0; s < 3; s++) v[s] = *(const float4*)(xr + s * 256 + lane * 4);

    float sum = 0.f;
    #pragma unroll
    for (int s = 0; s < 3; s++) sum += v[s].x + v[s].y + v[s].z + v[s].w;
    #pragma unroll
    for (int off = 1; off < 64; off <<= 1) sum += __shfl_xor(sum, off, 64);
    const float mu = sum * (1.0f / ND);

    float var = 0.f;
    #pragma unroll
    for (int s = 0; s < 3; s++) {
        float a0 = v[s].x - mu, a1 = v[s].y - mu, a2 = v[s].z - mu, a3 = v[s].w - mu;
        var += a0 * a0 + a1 * a1 + a2 * a2 + a3 * a3;
    }
    #pragma unroll
    for (int off = 1; off < 64; off <<= 1) var += __shfl_xor(var, off, 64);
    const float rstd = rsqrtf(var * (1.0f / ND) + LN_EPS);

    #pragma unroll
    for (int s = 0; s < 3; s++) {
        const int col = s * 256 + lane * 4;
        float4 w4 = *(const float4*)(w + col);
        float4 b4 = *(const float4*)(b + col);
        ushort4 r;
        r.x = f2bf((v[s].x - mu) * rstd * w4.x + b4.x);
        r.y = f2bf((v[s].y - mu) * rstd * w4.y + b4.y);
        r.z = f2bf((v[s].z - mu) * rstd * w4.z + b4.z);
        r.w = f2bf((v[s].w - mu) * rstd * w4.w + b4.w);
        *(ushort4*)(out + (size_t)row * ND + col) = r;
    }
}

// ---------------- bf16 MFMA GEMM, double-buffered pipeline (128x128) -----------
// Kept for the two N=768 GEMMs, bijective XCD-chunk swizzle (grids %8==0).
// Row-pair LDS swizzle (verified round 9: fcproj conflicts 4.7M -> off top-5).
// phys(r,c) = (r>>1)*128B + ((((r&1)<<2)|c)^((r>>1)&7))*16B; inverse applied on
// the GLOBAL source (linear LDS dest, rule #21); frag-read rows are 16-multiple
// + fcol so (pair&7) == fcol>>1, lane-uniform.
// EPI: 1 = +bias+resid -> fp32
template <int EPI>
__global__ __launch_bounds__(256) void gemm_bt(const ushort_t* __restrict__ A,
                                               const ushort_t* __restrict__ Bt,
                                               const float* __restrict__ bias,
                                               const float* __restrict__ resid,
                                               void* __restrict__ Cout,
                                               int M, int N, int K) {
    __shared__ __align__(16) ushort_t smem[2][2][128 * 32];  // [buf][A/B][...]

    const int tid  = threadIdx.x;
    const int nwg   = gridDim.x * gridDim.y;
    const int flatb = blockIdx.y * gridDim.x + blockIdx.x;
    const int q8    = nwg >> 3;
    const int swz   = (flatb & 7) * q8 + (flatb >> 3);
    const int bm   = (swz / gridDim.x) * 128;
    const int bn   = (swz % gridDim.x) * 128;
    const int lane = tid & 63;
    const int wave = tid >> 6;
    const int wm   = (wave & 1) * 64;
    const int wn   = (wave >> 1) * 64;
    const int fcol = lane & 15;
    const int quad = lane >> 4;

    f32x4 acc[4][4] = {};

    auto issue = [&](int k0, int buf) {
        #pragma unroll
        for (int p = 0; p < 2; p++) {
            const int f = p * 256 + tid;            // [0,512): 128 rows x 4 chunks
            const int pr = f >> 3, s2 = (f & 7) ^ (pr & 7);
            const int r = pr * 2 + (s2 >> 2), c = s2 & 3;
            load_lds16(A  + (size_t)(bm + r) * K + k0 + c * 8, &smem[buf][0][f * 8]);
            load_lds16(Bt + (size_t)(bn + r) * K + k0 + c * 8, &smem[buf][1][f * 8]);
        }
    };

    // frag-read swizzle term: slot = (((fcol&1)<<2)|quad) ^ (fcol>>1)
    const int slr = ((((fcol & 1) << 2) | quad) ^ (fcol >> 1)) * 8;

    issue(0, 0);
    const int KT = K >> 5;
    for (int kt = 0; kt < KT; kt++) {
        const int cur = kt & 1;
        __syncthreads();
        if (kt + 1 < KT) issue((kt + 1) << 5, cur ^ 1);

        bf16x8 a[4], b[4];
        #pragma unroll
        for (int i = 0; i < 4; i++)
            a[i] = *(const bf16x8*)&smem[cur][0][((wm + i * 16 + fcol) >> 1) * 64 + slr];
        #pragma unroll
        for (int j = 0; j < 4; j++)
            b[j] = *(const bf16x8*)&smem[cur][1][((wn + j * 16 + fcol) >> 1) * 64 + slr];
        #pragma unroll
        for (int i = 0; i < 4; i++)
            #pragma unroll
            for (int j = 0; j < 4; j++)
                acc[i][j] = __builtin_amdgcn_mfma_f32_16x16x32_bf16(a[i], b[j], acc[i][j], 0, 0, 0);
    }

    if (EPI == 1) {
        #pragma unroll
        for (int j = 0; j < 4; j++) {
            const int gcol = bn + wn + j * 16 + fcol;
            const float bs = bias[gcol];
            #pragma unroll
            for (int i = 0; i < 4; i++) {
                #pragma unroll
                for (int r = 0; r < 4; r++) {
                    const int grow = bm + wm + i * 16 + quad * 4 + r;
                    float val = acc[i][j][r] + bs + resid[(size_t)grow * N + gcol];
                    ((float*)Cout)[(size_t)grow * N + gcol] = val;
                }
            }
        }
    } else {
        __syncthreads();
        ushort_t* Cs = &smem[0][0][0] + wave * (64 * 40);
        #pragma unroll
        for (int hh = 0; hh < 2; hh++) {
            #pragma unroll
            for (int jj = 0; jj < 2; jj++) {
                const int j = hh * 2 + jj;
                const float bs = bias[bn + wn + j * 16 + fcol];
                #pragma unroll
                for (int i = 0; i < 4; i++) {
                    #pragma unroll
                    for (int r = 0; r < 4; r++) {
                        float val = acc[i][j][r] + bs;
                        if (EPI == 2) {
                            float y = 0.7978845608028654f * (val + 0.044715f * val * val * val);
                            float t = 1.0f - 2.0f / (1.0f + __expf(2.0f * y));
                            val = 0.5f * val * (1.0f + t);
                        }
                        const int lr = i * 16 + quad * 4 + r;
                        Cs[lr * 40 + jj * 16 + fcol] = f2bf(val);
                    }
                }
            }
            #pragma unroll
            for (int p = 0; p < 4; p++) {
                const int cid = p * 64 + lane;
                const int lr = cid >> 2, ck = cid & 3;
                bf16x8 vv = *(const bf16x8*)&Cs[lr * 40 + ck * 8];
                *(bf16x8*)((ushort_t*)Cout + (size_t)(bm + wm + lr) * N + bn + wn + hh * 32 + ck * 8) = vv;
            }
        }
    }
}

// ---------------- 128x256 BK=32 GEMM: counted-vmcnt + 2 blocks/CU --------------
// ROUND-8 VERSION RESTORED (61.0 us fc, conflicts 196K, harness-verified).
// Round-9's 3-slot ring REGRESSED to 82.8 us (depth-2 is this structure's
// optimum: deeper prefetch adds LDS-DMA/L2 pressure during the read+MFMA phase
// without reducing the drain count). Row-pair swizzle retained:
//   phys(r,c) = (r>>1)*128 + ((((r&1)<<2)|c) ^ ((r>>1)&7)) * 16  (2-way, free)
// Ledger: stage = exactly 3 global_load_lds; VMW(3) counted waits (t+1 landed).
// EPI: 0 = +bias -> bf16;  2 = +bias,gelu(tanh) -> bf16
template <int EPI, int NN, int KK>
__global__ __launch_bounds__(512, 4) void gemm128n(const ushort_t* __restrict__ A,
                                                   const ushort_t* __restrict__ Bt,
                                                   const float* __restrict__ bias,
                                                   ushort_t* __restrict__ Cout) {
    __shared__ __align__(16) ushort_t lds[24576];   // 48 KB: A 2x4096, B 2x8192 ushorts

    const int tid  = threadIdx.x;
    const int lane = tid & 63;
    const int wave = tid >> 6;     // 0..7
    const int wr   = wave >> 2;    // 0..1  (64-row half)
    const int wn   = wave & 3;     // 0..3  (64-col quarter)
    const int fcol = lane & 15;
    const int quad = lane >> 4;

    // bijective XCD-chunk swizzle (nwg = 576 / 768, both % 8 == 0)
    const int nwg   = gridDim.x * gridDim.y;
    const int flatb = blockIdx.y * gridDim.x + blockIdx.x;
    const int q8    = nwg >> 3;
    const int swz   = (flatb & 7) * q8 + (flatb >> 3);
    const int bm    = (swz / gridDim.x) * 128;
    const int bn    = (swz % gridDim.x) * 256;

    constexpr int KTILES = KK >> 5;   // 32-wide K tiles (24 for K=768)

    f32x4 acc[4][4] = {};             // 64 regs: wave's 64x64 output
    bf16x8 ra[4], rbv[4];

    // fragment-read bases (row-pair swizzle): pair = row>>1, pair&7 == fcol>>1
    // for all fragment rows (row = 16-multiple + fcol), so the XOR is lane-const.
    const unsigned ldsb = (unsigned)(size_t)(const __attribute__((address_space(3))) ushort_t*)lds;
    const unsigned slotr = (unsigned)(((((fcol & 1) << 2) | quad) ^ (fcol >> 1)) * 16);
    const unsigned baseA = ldsb + (unsigned)((wr * 32 + (fcol >> 1)) * 128) + slotr;
    const unsigned baseB = ldsb + 16384u + (unsigned)((wn * 32 + (fcol >> 1)) * 128) + slotr;

    auto stage = [&](int kt) {   // exactly 3 global_load_lds per thread
        const int kk = (kt < KTILES ? kt : 0) << 5;   // clamp keeps vmcnt ledger
        ushort_t* dstA = lds + (kt & 1) * 4096;
        {
            const int f = tid;                         // 512 loads cover 128x32
            const int pr = f >> 3, s2 = (f & 7) ^ (pr & 7);
            const int r = pr * 2 + (s2 >> 2), c = s2 & 3;
            load_lds16(A + (size_t)(bm + r) * KK + kk + c * 8, dstA + f * 8);
        }
        ushort_t* dstB = lds + 8192 + (kt & 1) * 8192;
        #pragma unroll
        for (int p = 0; p < 2; p++) {                  // 1024 loads cover 256x32
            const int f = (p << 9) + tid;
            const int pr = f >> 3, s2 = (f & 7) ^ (pr & 7);
            const int r = pr * 2 + (s2 >> 2), c = s2 & 3;
            load_lds16(Bt + (size_t)(bn + r) * KK + kk + c * 8, dstB + f * 8);
        }
    };

#define RD_T(CUR) {                                                        \
    ra[0]  = ds_read16o<(CUR) * 8192 + 0   >(baseA);                       \
    ra[1]  = ds_read16o<(CUR) * 8192 + 1024>(baseA);                       \
    ra[2]  = ds_read16o<(CUR) * 8192 + 2048>(baseA);                       \
    ra[3]  = ds_read16o<(CUR) * 8192 + 3072>(baseA);                       \
    rbv[0] = ds_read16o<(CUR) * 16384 + 0   >(baseB);                      \
    rbv[1] = ds_read16o<(CUR) * 16384 + 1024>(baseB);                      \
    rbv[2] = ds_read16o<(CUR) * 16384 + 2048>(baseB);                      \
    rbv[3] = ds_read16o<(CUR) * 16384 + 3072>(baseB); }
#define LGKM0() { asm volatile("s_waitcnt lgkmcnt(0)" ::: "memory");       \
    __builtin_amdgcn_sched_barrier(0); }
#define MMA16() {                                                          \
    __builtin_amdgcn_s_setprio(1);                                         \
    _Pragma("unroll") for (int i = 0; i < 4; i++)                          \
    _Pragma("unroll") for (int j = 0; j < 4; j++)                          \
        acc[i][j] = __builtin_amdgcn_mfma_f32_16x16x32_bf16(               \
            ra[i], rbv[j], acc[i][j], 0, 0, 0);                            \
    __builtin_amdgcn_s_setprio(0);                                         \
    __builtin_amdgcn_sched_barrier(0); }
#define VMW3() asm volatile("s_waitcnt vmcnt(3)" ::: "memory")
#define BARR() asm volatile("s_barrier" ::: "memory")

    stage(0); stage(1);
    VMW3();                       // tile0's 3 oldest loads landed
    BARR();

    #pragma unroll 1
    for (int it = 0; it < KTILES / 2; ++it) {
        const int t = it << 1;
        // even tile -> slot 0
        RD_T(0);
        LGKM0();
        MMA16();
        BARR();                   // all waves done reading slot 0
        stage(t + 2);             // overwrite slot 0 (WAR-safe)
        VMW3();                   // tile t+1 landed (own-wave)
        BARR();                   // publish block-wide
        // odd tile -> slot 1
        RD_T(1);
        LGKM0();
        MMA16();
        BARR();
        stage(t + 3);
        VMW3();
        BARR();
    }

    // full drain before LDS reuse
    asm volatile("s_waitcnt vmcnt(0) lgkmcnt(0)" ::: "memory");
    BARR();

    // epilogue: per-wave 32-row LDS staging (32x72 per wave = 36 KB total)
    ushort_t* Cs = lds + wave * (32 * 72);
    #pragma unroll
    for (int h = 0; h < 2; h++) {
        #pragma unroll
        for (int j = 0; j < 4; j++) {
            const float bs = bias[bn + wn * 64 + j * 16 + fcol];
            #pragma unroll
            for (int i2 = 0; i2 < 2; i2++) {
                #pragma unroll
                for (int r = 0; r < 4; r++) {
                    float val = acc[h * 2 + i2][j][r] + bs;
                    if (EPI == 2) {
                        float y = 0.7978845608028654f * (val + 0.044715f * val * val * val);
                        float t = 1.0f - 2.0f / (1.0f + __expf(2.0f * y));
                        val = 0.5f * val * (1.0f + t);
                    }
                    Cs[(i2 * 16 + quad * 4 + r) * 72 + j * 16 + fcol] = f2bf(val);
                }
            }
        }
        __builtin_amdgcn_sched_barrier(0);   // order within-wave store->load
        #pragma unroll
        for (int p = 0; p < 4; p++) {
            const int cid = (p << 6) + lane;
            const int lr = cid >> 3, ck = cid & 7;
            bf16x8 vv = *(const bf16x8*)&Cs[lr * 72 + ck * 8];
            *(bf16x8*)(Cout + (size_t)(bm + wr * 64 + h * 32 + lr) * NN + bn + wn * 64 + ck * 8) = vv;
        }
        __builtin_amdgcn_sched_barrier(0);
    }
#undef RD_T
#undef LGKM0
#undef MMA16
#undef VMW3
#undef BARR
}

// ---------------- MFMA flash attention: no-max softmax, l via ones-MFMA --------
__global__ __launch_bounds__(256) void flash_attn_mfma(const ushort_t* __restrict__ qkvb,
                                                       const ushort_t* __restrict__ vT,
                                                       const int* __restrict__ amask,
                                                       ushort_t* __restrict__ out) {
    const int qt = 15 - blockIdx.x;   // heavy tiles first
    const int h  = blockIdx.y;
    const int b  = blockIdx.z;
    const int q0 = qt * 64;

    __shared__ __align__(16) ushort_t QPs[64 * 64];      // Q, then reused for P
    __shared__ __align__(16) ushort_t Ks[2][64 * 64];
    __shared__ __align__(16) ushort_t Vts[2][64 * 64];

    const int tid  = threadIdx.x;
    const int lane = tid & 63;
    const int wave = tid >> 6;
    const int fcol = lane & 15;
    const int quad = lane >> 4;
    const int wq0  = wave * 16;

    #pragma unroll
    for (int p = 0; p < 2; p++) {
        int flat = p * 256 + tid;
        int r = flat >> 3, c = (flat & 7) ^ (r & 7);
        load_lds16(qkvb + (size_t)(b * NT + q0 + r) * (3 * ND) + h * HD + c * 8, &QPs[flat * 8]);
    }
    __syncthreads();

    bf16x8 aQ[2];
    {
        const int qr = wq0 + fcol;
        #pragma unroll
        for (int ks = 0; ks < 2; ks++) {
            int c = ks * 4 + quad;
            aQ[ks] = *(const bf16x8*)&QPs[qr * 64 + ((c ^ (qr & 7)) * 8)];
        }
    }

    bf16x8 bones;
    #pragma unroll
    for (int i = 0; i < 8; i++) bones[i] = (__bf16)1.0f;

    auto issueKV = [&](int cch, int buf) {
        const int kbase = cch * 64;
        #pragma unroll
        for (int p = 0; p < 2; p++) {
            int flat = p * 256 + tid;
            int r = flat >> 3, c = (flat & 7) ^ (r & 7);
            load_lds16(qkvb + (size_t)(b * NT + kbase + r) * (3 * ND) + ND + h * HD + c * 8,
                       &Ks[buf][flat * 8]);
            load_lds16(vT + ((size_t)((b * NH + h) * HD + r)) * NT + kbase + c * 8,
                       &Vts[buf][flat * 8]);
        }
    };

    f32x4 oacc[4] = {};
    f32x4 lacc = {};

    const int c_lo = (qt > 12) ? (qt - 12) : 0;
    issueKV(c_lo, 0);
    for (int cch = c_lo; cch <= qt; cch++) {
        const int cur = (cch - c_lo) & 1;
        const int kbase = cch * 64;
        __syncthreads();
        if (cch + 1 <= qt) issueKV(cch + 1, cur ^ 1);

        int am[4];
        #pragma unroll
        for (int jn = 0; jn < 4; jn++) am[jn] = amask[b * NT + kbase + jn * 16 + fcol];
        const int amok_lane = (am[0] != 0) & (am[1] != 0) & (am[2] != 0) & (am[3] != 0);
        const bool fast = (cch < qt) && (cch >= qt - 11) && __all(amok_lane);

        f32x4 sc[4] = {};
        #pragma unroll
        for (int ks = 0; ks < 2; ks++) {
            #pragma unroll
            for (int jn = 0; jn < 4; jn++) {
                const int kr = jn * 16 + fcol;
                bf16x8 bk = *(const bf16x8*)&Ks[cur][kr * 64 + (((ks * 4 + quad) ^ (kr & 7)) * 8)];
                sc[jn] = __builtin_amdgcn_mfma_f32_16x16x32_bf16(aQ[ks], bk, sc[jn], 0, 0, 0);
            }
        }

        float pvv[4][4];
        if (fast) {
            #pragma unroll
            for (int jn = 0; jn < 4; jn++)
                #pragma unroll
                for (int r = 0; r < 4; r++)
                    pvv[jn][r] = __builtin_amdgcn_exp2f(sc[jn][r] * SCL2);
        } else {
            #pragma unroll
            for (int jn = 0; jn < 4; jn++) {
                const int jg = kbase + jn * 16 + fcol;
                const bool amok = (am[jn] != 0);
                #pragma unroll
                for (int r = 0; r < 4; r++) {
                    const int ig = q0 + wq0 + quad * 4 + r;
                    bool keep = (jg <= ig) && (jg >= ig - (WINDOW - 1)) && amok;
                    float s = keep ? sc[jn][r] * SCL2 : -1e38f;
                    pvv[jn][r] = __builtin_amdgcn_exp2f(s);
                }
            }
        }

        #pragma unroll
        for (int half = 0; half < 2; half++) {
            const int cbase = half * 4 + (fcol >> 2);
            const int off = (fcol & 3) * 2;
            #pragma unroll
            for (int r = 0; r < 4; r++) {
                const int row = wq0 + quad * 4 + r;
                unsigned int pk = (unsigned int)f2bf(pvv[half * 2][r]) |
                                  ((unsigned int)f2bf(pvv[half * 2 + 1][r]) << 16);
                *(unsigned int*)&QPs[row * 64 + ((cbase ^ (row & 7)) * 8) + off] = pk;
            }
        }

        #pragma unroll
        for (int ks = 0; ks < 2; ks++) {
            const int pr = wq0 + fcol;
            bf16x8 ap = *(const bf16x8*)&QPs[pr * 64 + (((ks * 4 + quad) ^ (pr & 7)) * 8)];
            lacc = __builtin_amdgcn_mfma_f32_16x16x32_bf16(ap, bones, lacc, 0, 0, 0);
            #pragma unroll
            for (int jd = 0; jd < 4; jd++) {
                const int vr = jd * 16 + fcol;
                bf16x8 bv = *(const bf16x8*)&Vts[cur][vr * 64 + (((ks * 4 + quad) ^ (vr & 7)) * 8)];
                oacc[jd] = __builtin_amdgcn_mfma_f32_16x16x32_bf16(ap, bv, oacc[jd], 0, 0, 0);
            }
        }
    }

    #pragma unroll
    for (int r = 0; r < 4; r++) {
        const float inv = 1.0f / lacc[r];
        const size_t row = (size_t)(b * NT + q0 + wq0 + quad * 4 + r);
        #pragma unroll
        for (int jd = 0; jd < 4; jd++)
            out[row * ND + h * HD + jd * 16 + fcol] = f2bf(oacc[jd][r] * inv);
    }
}

extern "C" void kernel_launch(void* const* d_in, const int* in_sizes, int n_in,
                              void* d_out, int out_size, void* d_ws, size_t ws_size,
                              hipStream_t stream) {
    const float* x        = (const float*)d_in[0];
    const int*   amask    = (const int*)  d_in[1];
    const float* ln1_w    = (const float*)d_in[2];
    const float* ln1_b    = (const float*)d_in[3];
    const float* w_attn   = (const float*)d_in[4];
    const float* b_attn   = (const float*)d_in[5];
    const float* w_proj   = (const float*)d_in[6];
    const float* b_proj   = (const float*)d_in[7];
    const float* ln2_w    = (const float*)d_in[8];
    const float* ln2_b    = (const float*)d_in[9];
    const float* w_fc     = (const float*)d_in[10];
    const float* b_fc     = (const float*)d_in[11];
    const float* w_fcp    = (const float*)d_in[12];
    const float* b_fcp    = (const float*)d_in[13];
    float* out = (float*)d_out;

    ushort_t* ws = (ushort_t*)d_ws;
    ushort_t* qkvb   = ws;                               // BT*3*ND
    ushort_t* x1b    = qkvb + (size_t)BT * 3 * ND;       // BT*ND
    ushort_t* attn_b = x1b + (size_t)BT * ND;            // BT*ND
    ushort_t* hbuf   = attn_b + (size_t)BT * ND;         // BT*4*ND
    ushort_t* vTb    = hbuf + (size_t)BT * 4 * ND;       // BT*ND
    ushort_t* wA_T   = vTb + (size_t)BT * ND;            // 2304*768
    ushort_t* wP_T   = wA_T + (size_t)2304 * 768;        // 768*768
    ushort_t* wF_T   = wP_T + (size_t)768 * 768;         // 3072*768
    ushort_t* wFP_T  = wF_T + (size_t)3072 * 768;        // 768*3072

    transpose_all<<<6912, 256, 0, stream>>>(w_attn, wA_T, w_proj, wP_T, w_fc, wF_T, w_fcp, wFP_T);

    ln_kernel<<<BT / 4, 256, 0, stream>>>(x, ln1_w, ln1_b, x1b);
    gemm128n<0, 2304, 768><<<dim3(2304 / 256, BT / 128), 512, 0, stream>>>(x1b, wA_T, b_attn, qkvb);
    transpose_v<<<dim3(16, NH, NB), 256, 0, stream>>>(qkvb, vTb);
    flash_attn_mfma<<<dim3(16, NH, NB), 256, 0, stream>>>(qkvb, vTb, amask, attn_b);
    gemm_bt<1><<<dim3(768 / 128, BT / 128), 256, 0, stream>>>(attn_b, wP_T, b_proj, x, out, BT, ND, ND);
    ln_kernel<<<BT / 4, 256, 0, stream>>>(out, ln2_w, ln2_b, x1b);
    gemm128n<2, 3072, 768><<<dim3(3072 / 256, BT / 128), 512, 0, stream>>>(x1b, wF_T, b_fc, hbuf);
    gemm_bt<1><<<dim3(768 / 128, BT / 128), 256, 0, stream>>>(hbuf, wFP_T, b_fcp, out, out, BT, ND, 4 * ND);
}

// Round 11
// 349.603 us; speedup vs baseline: 1.0253x; 1.0022x over previous
//
#include <hip/hip_runtime.h>
#include <hip/hip_bf16.h>
#include <math.h>

#define NB 8
#define NT 1024
#define ND 768
#define NH 12
#define HD 64
#define WINDOW 768
#define LN_EPS 1e-5f
#define NEGF -3.4028234663852886e38f
#define SCL2 0.18033688011112042f   // 0.125 * log2(e)

static const int BT = NB * NT;  // 8192 rows

typedef __bf16 bf16x8 __attribute__((ext_vector_type(8)));
typedef float  f32x4  __attribute__((ext_vector_type(4)));
typedef unsigned short ushort_t;

__device__ __forceinline__ unsigned short f2bf(float f) {
    __hip_bfloat16 h = __float2bfloat16(f);
    return __builtin_bit_cast(unsigned short, h);
}

// async global->LDS, 16B per lane. LDS dest = wave-uniform base + lane*16.
__device__ __forceinline__ void load_lds16(const void* g, void* l) {
    __builtin_amdgcn_global_load_lds((const __attribute__((address_space(1))) unsigned int*)g,
                                     (__attribute__((address_space(3))) unsigned int*)l,
                                     16, 0, 0);
}

// inline-asm ds_read_b128 with compile-time offset immediate: ONE base VGPR serves
// all fragment reads of a class (slot + subtile folded into offset:IMM).
template <int IMM>
__device__ __forceinline__ bf16x8 ds_read16o(unsigned base) {
    bf16x8 r;
    asm volatile("ds_read_b128 %0, %1 offset:%2" : "=v"(r) : "v"(base), "n"(IMM));
    return r;
}

// ---------------- all weight transposes fused: wT[n][k] = bf16(w[k][n]) --------
__global__ __launch_bounds__(256) void transpose_all(const float* __restrict__ w0, ushort_t* __restrict__ t0v,
                                                     const float* __restrict__ w1, ushort_t* __restrict__ t1v,
                                                     const float* __restrict__ w2, ushort_t* __restrict__ t2v,
                                                     const float* __restrict__ w3, ushort_t* __restrict__ t3v) {
    int bid = blockIdx.x;
    const float* w; ushort_t* wt; int K, N;
    if (bid < 1728)                    { w = w0; wt = t0v; K = 768;  N = 2304; }
    else if ((bid -= 1728) < 576)      { w = w1; wt = t1v; K = 768;  N = 768;  }
    else if ((bid -= 576) < 2304)      { w = w2; wt = t2v; K = 768;  N = 3072; }
    else       { bid -= 2304;            w = w3; wt = t3v; K = 3072; N = 768;  }
    const int nxt = N / 32;
    const int n0 = (bid % nxt) * 32, k0 = (bid / nxt) * 32;
    __shared__ float t[32][33];
    const int tx = threadIdx.x & 31, ty = threadIdx.x >> 5;  // 32 x 8
    for (int r = ty; r < 32; r += 8)
        t[r][tx] = w[(size_t)(k0 + r) * N + n0 + tx];
    __syncthreads();
    for (int r = ty; r < 32; r += 8)
        wt[(size_t)(n0 + r) * K + k0 + tx] = f2bf(t[tx][r]);
}

// ---------------- V transpose (pi-permuted keys): vT[b][h][d][t'] --------------
__global__ __launch_bounds__(256) void transpose_v(const ushort_t* __restrict__ qkvb,
                                                   ushort_t* __restrict__ vT) {
    const int t0 = blockIdx.x * 64;
    const int h = blockIdx.y, b = blockIdx.z;
    __shared__ ushort_t sm[64 * 72];
    const int tid = threadIdx.x;
    #pragma unroll
    for (int p = 0; p < 2; p++) {
        int idx = p * 256 + tid;
        int r = idx >> 3, c = idx & 7;
        *(bf16x8*)&sm[r * 72 + c * 8] =
            *(const bf16x8*)(qkvb + (size_t)(b * NT + t0 + r) * (3 * ND) + 2 * ND + h * HD + c * 8);
    }
    __syncthreads();
    #pragma unroll
    for (int p = 0; p < 2; p++) {
        int idx = p * 256 + tid;
        int d = idx >> 3, c2 = idx & 7;
        ushort_t tmp[8];
        #pragma unroll
        for (int j = 0; j < 8; j++) {
            int kp = c2 * 8 + j;
            int key = ((kp & 1) << 4) | ((kp >> 1) & 15) | (kp & 32);
            tmp[j] = sm[key * 72 + d];
        }
        *(bf16x8*)(vT + ((size_t)((b * NH + h) * HD + d)) * NT + t0 + c2 * 8) = *(bf16x8*)tmp;
    }
}

// ---------------- LayerNorm -> bf16: wave-per-row, shuffle reduce --------------
__global__ __launch_bounds__(256) void ln_kernel(const float* __restrict__ x,
                                                 const float* __restrict__ w,
                                                 const float* __restrict__ b,
                                                 ushort_t* __restrict__ out) {
    const int row  = blockIdx.x * 4 + (threadIdx.x >> 6);
    const int lane = threadIdx.x & 63;
    const float* xr = x + (size_t)row * ND;

    float4 v[3];
    #pragma unroll
    for (int s = 0; s < 3; s++) v[s] = *(const float4*)(xr + s * 256 + lane * 4);

    float sum = 0.f;
    #pragma unroll
    for (int s = 0; s < 3; s++) sum += v[s].x + v[s].y + v[s].z + v[s].w;
    #pragma unroll
    for (int off = 1; off < 64; off <<= 1) sum += __shfl_xor(sum, off, 64);
    const float mu = sum * (1.0f / ND);

    float var = 0.f;
    #pragma unroll
    for (int s = 0; s < 3; s++) {
        float a0 = v[s].x - mu, a1 = v[s].y - mu, a2 = v[s].z - mu, a3 = v[s].w - mu;
        var += a0 * a0 + a1 * a1 + a2 * a2 + a3 * a3;
    }
    #pragma unroll
    for (int off = 1; off < 64; off <<= 1) var += __shfl_xor(var, off, 64);
    const float rstd = rsqrtf(var * (1.0f / ND) + LN_EPS);

    #pragma unroll
    for (int s = 0; s < 3; s++) {
        const int col = s * 256 + lane * 4;
        float4 w4 = *(const float4*)(w + col);
        float4 b4 = *(const float4*)(b + col);
        ushort4 r;
        r.x = f2bf((v[s].x - mu) * rstd * w4.x + b4.x);
        r.y = f2bf((v[s].y - mu) * rstd * w4.y + b4.y);
        r.z = f2bf((v[s].z - mu) * rstd * w4.z + b4.z);
        r.w = f2bf((v[s].w - mu) * rstd * w4.w + b4.w);
        *(ushort4*)(out + (size_t)row * ND + col) = r;
    }
}

// ---------------- bf16 MFMA GEMM, double-buffered pipeline (128x128) -----------
// Kept for the two N=768 GEMMs, bijective XCD-chunk swizzle (grids %8==0).
// Row-pair LDS swizzle (verified round 9). Round-11: per-thread source pointers
// hoisted out of issue() — the swizzle decomposition and 64-bit row*K address
// are k0-invariant; issue(k0) is now 4 loads at base + k0 (uniform offset).
// EPI: 1 = +bias+resid -> fp32
template <int EPI>
__global__ __launch_bounds__(256) void gemm_bt(const ushort_t* __restrict__ A,
                                               const ushort_t* __restrict__ Bt,
                                               const float* __restrict__ bias,
                                               const float* __restrict__ resid,
                                               void* __restrict__ Cout,
                                               int M, int N, int K) {
    __shared__ __align__(16) ushort_t smem[2][2][128 * 32];  // [buf][A/B][...]

    const int tid  = threadIdx.x;
    const int nwg   = gridDim.x * gridDim.y;
    const int flatb = blockIdx.y * gridDim.x + blockIdx.x;
    const int q8    = nwg >> 3;
    const int swz   = (flatb & 7) * q8 + (flatb >> 3);
    const int bm   = (swz / gridDim.x) * 128;
    const int bn   = (swz % gridDim.x) * 128;
    const int lane = tid & 63;
    const int wave = tid >> 6;
    const int wm   = (wave & 1) * 64;
    const int wn   = (wave >> 1) * 64;
    const int fcol = lane & 15;
    const int quad = lane >> 4;

    f32x4 acc[4][4] = {};

    // hoisted per-thread staging sources (k0-invariant; row-pair swizzle inverse)
    const ushort_t *gA0, *gA1, *gB0, *gB1;
    {
        int f = tid, pr = f >> 3, s2 = (f & 7) ^ (pr & 7);
        int r = pr * 2 + (s2 >> 2), c = s2 & 3;
        gA0 = A  + (size_t)(bm + r) * K + c * 8;
        gB0 = Bt + (size_t)(bn + r) * K + c * 8;
        f = 256 + tid; pr = f >> 3; s2 = (f & 7) ^ (pr & 7);
        r = pr * 2 + (s2 >> 2); c = s2 & 3;
        gA1 = A  + (size_t)(bm + r) * K + c * 8;
        gB1 = Bt + (size_t)(bn + r) * K + c * 8;
    }

    auto issue = [&](int k0, int buf) {
        load_lds16(gA0 + k0, &smem[buf][0][tid * 8]);
        load_lds16(gB0 + k0, &smem[buf][1][tid * 8]);
        load_lds16(gA1 + k0, &smem[buf][0][(256 + tid) * 8]);
        load_lds16(gB1 + k0, &smem[buf][1][(256 + tid) * 8]);
    };

    // frag-read swizzle term: slot = (((fcol&1)<<2)|quad) ^ (fcol>>1)
    const int slr = ((((fcol & 1) << 2) | quad) ^ (fcol >> 1)) * 8;

    issue(0, 0);
    const int KT = K >> 5;
    for (int kt = 0; kt < KT; kt++) {
        const int cur = kt & 1;
        __syncthreads();
        if (kt + 1 < KT) issue((kt + 1) << 5, cur ^ 1);

        bf16x8 a[4], b[4];
        #pragma unroll
        for (int i = 0; i < 4; i++)
            a[i] = *(const bf16x8*)&smem[cur][0][((wm + i * 16 + fcol) >> 1) * 64 + slr];
        #pragma unroll
        for (int j = 0; j < 4; j++)
            b[j] = *(const bf16x8*)&smem[cur][1][((wn + j * 16 + fcol) >> 1) * 64 + slr];
        #pragma unroll
        for (int i = 0; i < 4; i++)
            #pragma unroll
            for (int j = 0; j < 4; j++)
                acc[i][j] = __builtin_amdgcn_mfma_f32_16x16x32_bf16(a[i], b[j], acc[i][j], 0, 0, 0);
    }

    if (EPI == 1) {
        #pragma unroll
        for (int j = 0; j < 4; j++) {
            const int gcol = bn + wn + j * 16 + fcol;
            const float bs = bias[gcol];
            #pragma unroll
            for (int i = 0; i < 4; i++) {
                #pragma unroll
                for (int r = 0; r < 4; r++) {
                    const int grow = bm + wm + i * 16 + quad * 4 + r;
                    float val = acc[i][j][r] + bs + resid[(size_t)grow * N + gcol];
                    ((float*)Cout)[(size_t)grow * N + gcol] = val;
                }
            }
        }
    } else {
        __syncthreads();
        ushort_t* Cs = &smem[0][0][0] + wave * (64 * 40);
        #pragma unroll
        for (int hh = 0; hh < 2; hh++) {
            #pragma unroll
            for (int jj = 0; jj < 2; jj++) {
                const int j = hh * 2 + jj;
                const float bs = bias[bn + wn + j * 16 + fcol];
                #pragma unroll
                for (int i = 0; i < 4; i++) {
                    #pragma unroll
                    for (int r = 0; r < 4; r++) {
                        float val = acc[i][j][r] + bs;
                        if (EPI == 2) {
                            float y = 0.7978845608028654f * (val + 0.044715f * val * val * val);
                            float t = 1.0f - 2.0f / (1.0f + __expf(2.0f * y));
                            val = 0.5f * val * (1.0f + t);
                        }
                        const int lr = i * 16 + quad * 4 + r;
                        Cs[lr * 40 + jj * 16 + fcol] = f2bf(val);
                    }
                }
            }
            #pragma unroll
            for (int p = 0; p < 4; p++) {
                const int cid = p * 64 + lane;
                const int lr = cid >> 2, ck = cid & 3;
                bf16x8 vv = *(const bf16x8*)&Cs[lr * 40 + ck * 8];
                *(bf16x8*)((ushort_t*)Cout + (size_t)(bm + wm + lr) * N + bn + wn + hh * 32 + ck * 8) = vv;
            }
        }
    }
}

// ---------------- 128x256 BK=32 GEMM: counted-vmcnt + 2 blocks/CU --------------
// Round-8 structure (61.0 us fc, conflicts 196K; depth-2 optimum — depth-3
// regressed to 82.8). Round-11: per-thread staging sources hoisted — the
// row-pair-swizzle decomposition and 64-bit row*K addresses are kt-invariant,
// so stage(kt) is now 3 loads at base + kk (kk uniform). Attacks the measured
// VALUBusy 40.6% (minus MFMA-issue ~26% -> ~15% real VALU, mostly addr calc
// serialized between barrier and load issue). Ledger unchanged: 3 loads/stage,
// VMW(3) counted waits.
// EPI: 0 = +bias -> bf16;  2 = +bias,gelu(tanh) -> bf16
template <int EPI, int NN, int KK>
__global__ __launch_bounds__(512, 4) void gemm128n(const ushort_t* __restrict__ A,
                                                   const ushort_t* __restrict__ Bt,
                                                   const float* __restrict__ bias,
                                                   ushort_t* __restrict__ Cout) {
    __shared__ __align__(16) ushort_t lds[24576];   // 48 KB: A 2x4096, B 2x8192 ushorts

    const int tid  = threadIdx.x;
    const int lane = tid & 63;
    const int wave = tid >> 6;     // 0..7
    const int wr   = wave >> 2;    // 0..1  (64-row half)
    const int wn   = wave & 3;     // 0..3  (64-col quarter)
    const int fcol = lane & 15;
    const int quad = lane >> 4;

    // bijective XCD-chunk swizzle (nwg = 576 / 768, both % 8 == 0)
    const int nwg   = gridDim.x * gridDim.y;
    const int flatb = blockIdx.y * gridDim.x + blockIdx.x;
    const int q8    = nwg >> 3;
    const int swz   = (flatb & 7) * q8 + (flatb >> 3);
    const int bm    = (swz / gridDim.x) * 128;
    const int bn    = (swz % gridDim.x) * 256;

    constexpr int KTILES = KK >> 5;   // 32-wide K tiles (24 for K=768)

    f32x4 acc[4][4] = {};             // 64 regs: wave's 64x64 output
    bf16x8 ra[4], rbv[4];

    // fragment-read bases (row-pair swizzle): pair = row>>1, pair&7 == fcol>>1
    const unsigned ldsb = (unsigned)(size_t)(const __attribute__((address_space(3))) ushort_t*)lds;
    const unsigned slotr = (unsigned)(((((fcol & 1) << 2) | quad) ^ (fcol >> 1)) * 16);
    const unsigned baseA = ldsb + (unsigned)((wr * 32 + (fcol >> 1)) * 128) + slotr;
    const unsigned baseB = ldsb + 16384u + (unsigned)((wn * 32 + (fcol >> 1)) * 128) + slotr;

    // hoisted per-thread staging sources (kt-invariant; row-pair swizzle inverse)
    const ushort_t *srcA, *srcB0, *srcB1;
    {
        int f = tid, pr = f >> 3, s2 = (f & 7) ^ (pr & 7);
        int r = pr * 2 + (s2 >> 2), c = s2 & 3;
        srcA  = A  + (size_t)(bm + r) * KK + c * 8;
        srcB0 = Bt + (size_t)(bn + r) * KK + c * 8;
        f = 512 + tid; pr = f >> 3; s2 = (f & 7) ^ (pr & 7);
        r = pr * 2 + (s2 >> 2); c = s2 & 3;
        srcB1 = Bt + (size_t)(bn + r) * KK + c * 8;
    }

    auto stage = [&](int kt) {   // exactly 3 global_load_lds per thread
        const int kk = (kt < KTILES ? kt : 0) << 5;   // clamp keeps vmcnt ledger
        ushort_t* dstA = lds + (kt & 1) * 4096;
        ushort_t* dstB = lds + 8192 + (kt & 1) * 8192;
        load_lds16(srcA  + kk, dstA + tid * 8);
        load_lds16(srcB0 + kk, dstB + tid * 8);
        load_lds16(srcB1 + kk, dstB + (512 + tid) * 8);
    };

#define RD_T(CUR) {                                                        \
    ra[0]  = ds_read16o<(CUR) * 8192 + 0   >(baseA);                       \
    ra[1]  = ds_read16o<(CUR) * 8192 + 1024>(baseA);                       \
    ra[2]  = ds_read16o<(CUR) * 8192 + 2048>(baseA);                       \
    ra[3]  = ds_read16o<(CUR) * 8192 + 3072>(baseA);                       \
    rbv[0] = ds_read16o<(CUR) * 16384 + 0   >(baseB);                      \
    rbv[1] = ds_read16o<(CUR) * 16384 + 1024>(baseB);                      \
    rbv[2] = ds_read16o<(CUR) * 16384 + 2048>(baseB);                      \
    rbv[3] = ds_read16o<(CUR) * 16384 + 3072>(baseB); }
#define LGKM0() { asm volatile("s_waitcnt lgkmcnt(0)" ::: "memory");       \
    __builtin_amdgcn_sched_barrier(0); }
#define MMA16() {                                                          \
    __builtin_amdgcn_s_setprio(1);                                         \
    _Pragma("unroll") for (int i = 0; i < 4; i++)                          \
    _Pragma("unroll") for (int j = 0; j < 4; j++)                          \
        acc[i][j] = __builtin_amdgcn_mfma_f32_16x16x32_bf16(               \
            ra[i], rbv[j], acc[i][j], 0, 0, 0);                            \
    __builtin_amdgcn_s_setprio(0);                                         \
    __builtin_amdgcn_sched_barrier(0); }
#define VMW3() asm volatile("s_waitcnt vmcnt(3)" ::: "memory")
#define BARR() asm volatile("s_barrier" ::: "memory")

    stage(0); stage(1);
    VMW3();                       // tile0's 3 oldest loads landed
    BARR();

    #pragma unroll 1
    for (int it = 0; it < KTILES / 2; ++it) {
        const int t = it << 1;
        // even tile -> slot 0
        RD_T(0);
        LGKM0();
        MMA16();
        BARR();                   // all waves done reading slot 0
        stage(t + 2);             // overwrite slot 0 (WAR-safe)
        VMW3();                   // tile t+1 landed (own-wave)
        BARR();                   // publish block-wide
        // odd tile -> slot 1
        RD_T(1);
        LGKM0();
        MMA16();
        BARR();
        stage(t + 3);
        VMW3();
        BARR();
    }

    // full drain before LDS reuse
    asm volatile("s_waitcnt vmcnt(0) lgkmcnt(0)" ::: "memory");
    BARR();

    // epilogue: per-wave 32-row LDS staging (32x72 per wave = 36 KB total)
    ushort_t* Cs = lds + wave * (32 * 72);
    #pragma unroll
    for (int h = 0; h < 2; h++) {
        #pragma unroll
        for (int j = 0; j < 4; j++) {
            const float bs = bias[bn + wn * 64 + j * 16 + fcol];
            #pragma unroll
            for (int i2 = 0; i2 < 2; i2++) {
                #pragma unroll
                for (int r = 0; r < 4; r++) {
                    float val = acc[h * 2 + i2][j][r] + bs;
                    if (EPI == 2) {
                        float y = 0.7978845608028654f * (val + 0.044715f * val * val * val);
                        float t = 1.0f - 2.0f / (1.0f + __expf(2.0f * y));
                        val = 0.5f * val * (1.0f + t);
                    }
                    Cs[(i2 * 16 + quad * 4 + r) * 72 + j * 16 + fcol] = f2bf(val);
                }
            }
        }
        __builtin_amdgcn_sched_barrier(0);   // order within-wave store->load
        #pragma unroll
        for (int p = 0; p < 4; p++) {
            const int cid = (p << 6) + lane;
            const int lr = cid >> 3, ck = cid & 7;
            bf16x8 vv = *(const bf16x8*)&Cs[lr * 72 + ck * 8];
            *(bf16x8*)(Cout + (size_t)(bm + wr * 64 + h * 32 + lr) * NN + bn + wn * 64 + ck * 8) = vv;
        }
        __builtin_amdgcn_sched_barrier(0);
    }
#undef RD_T
#undef LGKM0
#undef MMA16
#undef VMW3
#undef BARR
}

// ---------------- MFMA flash attention: no-max softmax, l via ones-MFMA --------
__global__ __launch_bounds__(256) void flash_attn_mfma(const ushort_t* __restrict__ qkvb,
                                                       const ushort_t* __restrict__ vT,
                                                       const int* __restrict__ amask,
                                                       ushort_t* __restrict__ out) {
    const int qt = 15 - blockIdx.x;   // heavy tiles first
    const int h  = blockIdx.y;
    const int b  = blockIdx.z;
    const int q0 = qt * 64;

    __shared__ __align__(16) ushort_t QPs[64 * 64];      // Q, then reused for P
    __shared__ __align__(16) ushort_t Ks[2][64 * 64];
    __shared__ __align__(16) ushort_t Vts[2][64 * 64];

    const int tid  = threadIdx.x;
    const int lane = tid & 63;
    const int wave = tid >> 6;
    const int fcol = lane & 15;
    const int quad = lane >> 4;
    const int wq0  = wave * 16;

    #pragma unroll
    for (int p = 0; p < 2; p++) {
        int flat = p * 256 + tid;
        int r = flat >> 3, c = (flat & 7) ^ (r & 7);
        load_lds16(qkvb + (size_t)(b * NT + q0 + r) * (3 * ND) + h * HD + c * 8, &QPs[flat * 8]);
    }
    __syncthreads();

    bf16x8 aQ[2];
    {
        const int qr = wq0 + fcol;
        #pragma unroll
        for (int ks = 0; ks < 2; ks++) {
            int c = ks * 4 + quad;
            aQ[ks] = *(const bf16x8*)&QPs[qr * 64 + ((c ^ (qr & 7)) * 8)];
        }
    }

    bf16x8 bones;
    #pragma unroll
    for (int i = 0; i < 8; i++) bones[i] = (__bf16)1.0f;

    auto issueKV = [&](int cch, int buf) {
        const int kbase = cch * 64;
        #pragma unroll
        for (int p = 0; p < 2; p++) {
            int flat = p * 256 + tid;
            int r = flat >> 3, c = (flat & 7) ^ (r & 7);
            load_lds16(qkvb + (size_t)(b * NT + kbase + r) * (3 * ND) + ND + h * HD + c * 8,
                       &Ks[buf][flat * 8]);
            load_lds16(vT + ((size_t)((b * NH + h) * HD + r)) * NT + kbase + c * 8,
                       &Vts[buf][flat * 8]);
        }
    };

    f32x4 oacc[4] = {};
    f32x4 lacc = {};

    const int c_lo = (qt > 12) ? (qt - 12) : 0;
    issueKV(c_lo, 0);
    for (int cch = c_lo; cch <= qt; cch++) {
        const int cur = (cch - c_lo) & 1;
        const int kbase = cch * 64;
        __syncthreads();
        if (cch + 1 <= qt) issueKV(cch + 1, cur ^ 1);

        int am[4];
        #pragma unroll
        for (int jn = 0; jn < 4; jn++) am[jn] = amask[b * NT + kbase + jn * 16 + fcol];
        const int amok_lane = (am[0] != 0) & (am[1] != 0) & (am[2] != 0) & (am[3] != 0);
        const bool fast = (cch < qt) && (cch >= qt - 11) && __all(amok_lane);

        f32x4 sc[4] = {};
        #pragma unroll
        for (int ks = 0; ks < 2; ks++) {
            #pragma unroll
            for (int jn = 0; jn < 4; jn++) {
                const int kr = jn * 16 + fcol;
                bf16x8 bk = *(const bf16x8*)&Ks[cur][kr * 64 + (((ks * 4 + quad) ^ (kr & 7)) * 8)];
                sc[jn] = __builtin_amdgcn_mfma_f32_16x16x32_bf16(aQ[ks], bk, sc[jn], 0, 0, 0);
            }
        }

        float pvv[4][4];
        if (fast) {
            #pragma unroll
            for (int jn = 0; jn < 4; jn++)
                #pragma unroll
                for (int r = 0; r < 4; r++)
                    pvv[jn][r] = __builtin_amdgcn_exp2f(sc[jn][r] * SCL2);
        } else {
            #pragma unroll
            for (int jn = 0; jn < 4; jn++) {
                const int jg = kbase + jn * 16 + fcol;
                const bool amok = (am[jn] != 0);
                #pragma unroll
                for (int r = 0; r < 4; r++) {
                    const int ig = q0 + wq0 + quad * 4 + r;
                    bool keep = (jg <= ig) && (jg >= ig - (WINDOW - 1)) && amok;
                    float s = keep ? sc[jn][r] * SCL2 : -1e38f;
                    pvv[jn][r] = __builtin_amdgcn_exp2f(s);
                }
            }
        }

        #pragma unroll
        for (int half = 0; half < 2; half++) {
            const int cbase = half * 4 + (fcol >> 2);
            const int off = (fcol & 3) * 2;
            #pragma unroll
            for (int r = 0; r < 4; r++) {
                const int row = wq0 + quad * 4 + r;
                unsigned int pk = (unsigned int)f2bf(pvv[half * 2][r]) |
                                  ((unsigned int)f2bf(pvv[half * 2 + 1][r]) << 16);
                *(unsigned int*)&QPs[row * 64 + ((cbase ^ (row & 7)) * 8) + off] = pk;
            }
        }

        #pragma unroll
        for (int ks = 0; ks < 2; ks++) {
            const int pr = wq0 + fcol;
            bf16x8 ap = *(const bf16x8*)&QPs[pr * 64 + (((ks * 4 + quad) ^ (pr & 7)) * 8)];
            lacc = __builtin_amdgcn_mfma_f32_16x16x32_bf16(ap, bones, lacc, 0, 0, 0);
            #pragma unroll
            for (int jd = 0; jd < 4; jd++) {
                const int vr = jd * 16 + fcol;
                bf16x8 bv = *(const bf16x8*)&Vts[cur][vr * 64 + (((ks * 4 + quad) ^ (vr & 7)) * 8)];
                oacc[jd] = __builtin_amdgcn_mfma_f32_16x16x32_bf16(ap, bv, oacc[jd], 0, 0, 0);
            }
        }
    }

    #pragma unroll
    for (int r = 0; r < 4; r++) {
        const float inv = 1.0f / lacc[r];
        const size_t row = (size_t)(b * NT + q0 + wq0 + quad * 4 + r);
        #pragma unroll
        for (int jd = 0; jd < 4; jd++)
            out[row * ND + h * HD + jd * 16 + fcol] = f2bf(oacc[jd][r] * inv);
    }
}

extern "C" void kernel_launch(void* const* d_in, const int* in_sizes, int n_in,
                              void* d_out, int out_size, void* d_ws, size_t ws_size,
                              hipStream_t stream) {
    const float* x        = (const float*)d_in[0];
    const int*   amask    = (const int*)  d_in[1];
    const float* ln1_w    = (const float*)d_in[2];
    const float* ln1_b    = (const float*)d_in[3];
    const float* w_attn   = (const float*)d_in[4];
    const float* b_attn   = (const float*)d_in[5];
    const float* w_proj   = (const float*)d_in[6];
    const float* b_proj   = (const float*)d_in[7];
    const float* ln2_w    = (const float*)d_in[8];
    const float* ln2_b    = (const float*)d_in[9];
    const float* w_fc     = (const float*)d_in[10];
    const float* b_fc     = (const float*)d_in[11];
    const float* w_fcp    = (const float*)d_in[12];
    const float* b_fcp    = (const float*)d_in[13];
    float* out = (float*)d_out;

    ushort_t* ws = (ushort_t*)d_ws;
    ushort_t* qkvb   = ws;                               // BT*3*ND
    ushort_t* x1b    = qkvb + (size_t)BT * 3 * ND;       // BT*ND
    ushort_t* attn_b = x1b + (size_t)BT * ND;            // BT*ND
    ushort_t* hbuf   = attn_b + (size_t)BT * ND;         // BT*4*ND
    ushort_t* vTb    = hbuf + (size_t)BT * 4 * ND;       // BT*ND
    ushort_t* wA_T   = vTb + (size_t)BT * ND;            // 2304*768
    ushort_t* wP_T   = wA_T + (size_t)2304 * 768;        // 768*768
    ushort_t* wF_T   = wP_T + (size_t)768 * 768;         // 3072*768
    ushort_t* wFP_T  = wF_T + (size_t)3072 * 768;        // 768*3072

    transpose_all<<<6912, 256, 0, stream>>>(w_attn, wA_T, w_proj, wP_T, w_fc, wF_T, w_fcp, wFP_T);

    ln_kernel<<<BT / 4, 256, 0, stream>>>(x, ln1_w, ln1_b, x1b);
    gemm128n<0, 2304, 768><<<dim3(2304 / 256, BT / 128), 512, 0, stream>>>(x1b, wA_T, b_attn, qkvb);
    transpose_v<<<dim3(16, NH, NB), 256, 0, stream>>>(qkvb, vTb);
    flash_attn_mfma<<<dim3(16, NH, NB), 256, 0, stream>>>(qkvb, vTb, amask, attn_b);
    gemm_bt<1><<<dim3(768 / 128, BT / 128), 256, 0, stream>>>(attn_b, wP_T, b_proj, x, out, BT, ND, ND);
    ln_kernel<<<BT / 4, 256, 0, stream>>>(out, ln2_w, ln2_b, x1b);
    gemm128n<2, 3072, 768><<<dim3(3072 / 256, BT / 128), 512, 0, stream>>>(x1b, wF_T, b_fc, hbuf);
    gemm_bt<1><<<dim3(768 / 128, BT / 128), 256, 0, stream>>>(hbuf, wFP_T, b_fcp, out, out, BT, ND, 4 * ND);
}